// Round 3
// baseline (287.794 us; speedup 1.0000x reference)
//
#include <hip/hip_runtime.h>

// Problem constants (fixed by the reference)
#define BB   16
#define NN   256
#define MM   12
#define HAc  64
#define Hh   4
#define DINc 192     // 2*HA + HB
#define A12LD 260    // LDS row stride (floats) for a1/a2/gc: 260%32=4 -> 2-way max, free

// ---------------- k0: P12 = atom_emb @ [W1 | W2]  (W1 = W_full rows 0..63,
// W2 = rows 64..127). P12: [4096][2048], cols 0..1023 = self-part, 1024..2047 = nbr-part.
__global__ __launch_bounds__(256) void k0_p12(
    const float* __restrict__ atom_emb,   // [4096,64]
    const float* __restrict__ W_full,     // [192,1024]
    float* __restrict__ p12)              // [4096,2048]
{
    __shared__ float sA[8][64];
    const int r0 = blockIdx.x * 8;
    const int t  = threadIdx.x;
    for (int e = t; e < 512; e += 256) sA[e >> 6][e & 63] = atom_emb[r0 * 64 + e];
    __syncthreads();

    const float4* W4 = (const float4*)W_full;   // [192][256] float4
    float4 acc0[8], acc1[8];
    #pragma unroll
    for (int r = 0; r < 8; ++r) {
        acc0[r] = make_float4(0.f, 0.f, 0.f, 0.f);
        acc1[r] = make_float4(0.f, 0.f, 0.f, 0.f);
    }
    for (int k = 0; k < 64; ++k) {
        float4 w0 = W4[k * 256 + t];           // W1 row k
        float4 w1 = W4[(k + 64) * 256 + t];    // W2 row k
        #pragma unroll
        for (int r = 0; r < 8; ++r) {
            float a = sA[r][k];
            acc0[r].x += a * w0.x; acc0[r].y += a * w0.y; acc0[r].z += a * w0.z; acc0[r].w += a * w0.w;
            acc1[r].x += a * w1.x; acc1[r].y += a * w1.y; acc1[r].z += a * w1.z; acc1[r].w += a * w1.w;
        }
    }
    float4* P4 = (float4*)p12;                  // row stride 512 float4
    #pragma unroll
    for (int r = 0; r < 8; ++r) {
        P4[(r0 + r) * 512 + t]       = acc0[r];
        P4[(r0 + r) * 512 + 256 + t] = acc1[r];
    }
}

// ---------------- k1: fused bond-GEMM + attention + gating + final GEMM.
// One block per (b,n) atom, 128 threads (2 waves).
// Thread t<64  owns gate quad t (cols 4t..4t+3)    and core quad t+64 (cols 256+4t..)
// Thread t>=64 owns a1 quad t+64 (cols 512+4(t-64)) and a2 quad t+128 (cols 768+4(t-64))
__global__ __launch_bounds__(128) void k1_fused(
    const float* __restrict__ nbr_emb,    // [B,N,M,64]
    const float* __restrict__ atom_mask,  // [B,N,1]
    const float* __restrict__ W_full,     // [192,1024] (rows 128..191 = W3 used here)
    const float* __restrict__ b_full,     // [1024]
    const float* __restrict__ W_final,    // [256,64]
    const float* __restrict__ b_final,    // [64]
    const int*   __restrict__ adj,        // [B,N,M]
    const float* __restrict__ p12,        // [4096,2048]
    float* __restrict__ pre)              // out: [B,N,M,64] pre-BN1
{
    __shared__ __align__(16) float nbT[64][16];      // 4 KB: nbr_emb^T; reused as `part` in phase E
    __shared__ __align__(16) float a12[24 * A12LD];  // 24.4 KB: a1 rows 0..11, a2 rows 12..23; reused as gc
    __shared__ __align__(16) float scr[Hh][MM][MM];  // 2.3 KB: scores/probs

    const int bn = blockIdx.x;            // b*256 + n
    const int b  = bn >> 8;
    const int t  = threadIdx.x;
    const float mask = atom_mask[bn];

    // ---- Phase A: stage nbr_emb^T via float4 loads: nbT[k][m] = nbr_emb[bn][m][k] ----
    for (int e4 = t; e4 < MM * 16; e4 += 128) {      // 192 float4 per block
        float4 v = ((const float4*)nbr_emb)[bn * (MM * 16) + e4];
        int m = e4 >> 4;
        int k = (e4 & 15) * 4;
        nbT[k][m] = v.x; nbT[k + 1][m] = v.y; nbT[k + 2][m] = v.z; nbT[k + 3][m] = v.w;
    }

    // ---- neighbor indices (block-uniform -> scalar loads) ----
    int nrow[MM];
    #pragma unroll
    for (int m = 0; m < MM; ++m) nrow[m] = b * NN + adj[bn * MM + m];

    // ---- acc init: P1[bn] + b_full + mask*P2[adj[m]] ----
    const int q0 = t + (t & 64);          // t<64 -> t ; t>=64 -> t+64
    const int q1 = q0 + 64;
    const float4* P4 = (const float4*)p12;
    const float4* B4 = (const float4*)b_full;
    float4 acc0[MM], acc1[MM];
    {
        float4 i0 = P4[bn * 512 + q0];
        float4 i1 = P4[bn * 512 + q1];
        float4 bb0 = B4[q0], bb1 = B4[q1];
        i0.x += bb0.x; i0.y += bb0.y; i0.z += bb0.z; i0.w += bb0.w;
        i1.x += bb1.x; i1.y += bb1.y; i1.z += bb1.z; i1.w += bb1.w;
        #pragma unroll
        for (int m = 0; m < MM; ++m) {
            float4 p0 = P4[nrow[m] * 512 + 256 + q0];
            float4 p1 = P4[nrow[m] * 512 + 256 + q1];
            acc0[m].x = i0.x + mask * p0.x; acc0[m].y = i0.y + mask * p0.y;
            acc0[m].z = i0.z + mask * p0.z; acc0[m].w = i0.w + mask * p0.w;
            acc1[m].x = i1.x + mask * p1.x; acc1[m].y = i1.y + mask * p1.y;
            acc1[m].z = i1.z + mask * p1.z; acc1[m].w = i1.w + mask * p1.w;
        }
    }
    __syncthreads();   // nbT ready

    // ---- Phase B: acc += nbr_emb @ W3  (W3 = W_full rows 128..191) ----
    const float4* W4 = (const float4*)W_full;
    for (int k = 0; k < 64; ++k) {
        float4 w0 = W4[(128 + k) * 256 + q0];
        float4 w1 = W4[(128 + k) * 256 + q1];
        const float4* tp = (const float4*)&nbT[k][0];
        float4 tA = tp[0], tB = tp[1], tC = tp[2];
        float tm[MM] = {tA.x, tA.y, tA.z, tA.w, tB.x, tB.y, tB.z, tB.w, tC.x, tC.y, tC.z, tC.w};
        #pragma unroll
        for (int m = 0; m < MM; ++m) {
            float s = tm[m];
            acc0[m].x += s * w0.x; acc0[m].y += s * w0.y; acc0[m].z += s * w0.z; acc0[m].w += s * w0.w;
            acc1[m].x += s * w1.x; acc1[m].y += s * w1.y; acc1[m].z += s * w1.z; acc1[m].w += s * w1.w;
        }
    }

    // ---- a1/a2 -> LDS (threads 64..127 only); gate/core stay in registers ----
    if (t >= 64) {
        const int lq = t - 64;            // local quad within chunk
        #pragma unroll
        for (int m = 0; m < MM; ++m) {
            *(float4*)&a12[m * A12LD + 4 * lq]        = acc0[m];   // a1[m]
            *(float4*)&a12[(12 + m) * A12LD + 4 * lq] = acc1[m];   // a2[m]
        }
    }
    __syncthreads();

    // ---- Phase C: scores[h][m][k] = 0.5 * dot(a1[m,h,:], a2[k,h,:]) + bias ----
    const float bias = (1.0f - mask) * (-10000.0f);
    for (int idx = t; idx < Hh * MM * MM; idx += 128) {
        int h = idx / (MM * MM);
        int r = idx - h * (MM * MM);
        int m = r / MM;
        int k = r - m * MM;
        const float4* p1 = (const float4*)&a12[m * A12LD + h * HAc];
        const float4* p2 = (const float4*)&a12[(12 + k) * A12LD + h * HAc];
        float s = 0.f;
        #pragma unroll
        for (int q = 0; q < 16; ++q) {
            float4 x = p1[q], y = p2[q];
            s += x.x * y.x + x.y * y.y + x.z * y.z + x.w * y.w;
        }
        scr[h][m][k] = s * 0.5f + bias;   // 1/sqrt(H) = 0.5
    }
    __syncthreads();

    // ---- softmax over k: one thread per (h,m) row ----
    if (t < Hh * MM) {
        float* row = &scr[0][0][0] + t * MM;
        float mx = row[0];
        #pragma unroll
        for (int k = 1; k < MM; ++k) mx = fmaxf(mx, row[k]);
        float e[MM];
        float sum = 0.f;
        #pragma unroll
        for (int k = 0; k < MM; ++k) { e[k] = __expf(row[k] - mx); sum += e[k]; }
        float inv = 1.0f / sum;
        #pragma unroll
        for (int k = 0; k < MM; ++k) row[k] = e[k] * inv;
    }
    __syncthreads();

    // ---- Phase D: ctx + relu + sigmoid(gate) -> gc (t<64; core/gate in regs) ----
    // gc[m][cc] written into a12 rows 0..11 (a1 space, dead now), cc = 4t..4t+3
    if (t < 64) {
        const int h = t >> 4;             // cols 4t..4t+3 never cross a 64-col head boundary
        #pragma unroll
        for (int m = 0; m < MM; ++m) {
            float sx = 0.f, sy = 0.f, sz = 0.f, sw = 0.f;
            #pragma unroll
            for (int k = 0; k < MM; ++k) {
                float p = scr[h][m][k];
                sx += p * acc1[k].x; sy += p * acc1[k].y;
                sz += p * acc1[k].z; sw += p * acc1[k].w;
            }
            float4 g;
            g.x = 1.0f / (1.0f + __expf(-acc0[m].x)) * fmaxf(sx, 0.f);
            g.y = 1.0f / (1.0f + __expf(-acc0[m].y)) * fmaxf(sy, 0.f);
            g.z = 1.0f / (1.0f + __expf(-acc0[m].z)) * fmaxf(sz, 0.f);
            g.w = 1.0f / (1.0f + __expf(-acc0[m].w)) * fmaxf(sw, 0.f);
            *(float4*)&a12[m * A12LD + 4 * t] = g;
        }
    }
    __syncthreads();

    // ---- Phase E: summed[m][j] = gc[m][:] @ W_final[:,j] + b_final[j] ----
    {
        const int w = t >> 6;
        const int j = t & 63;
        const float bf = b_final[j];
        float accf[MM];
        #pragma unroll
        for (int m = 0; m < MM; ++m) accf[m] = 0.f;
        const int c0 = w * 128;
        for (int c4 = 0; c4 < 32; ++c4) {
            const int c = c0 + c4 * 4;
            const float* wfp = W_final + c * HAc + j;
            float wf0 = wfp[0], wf1 = wfp[64], wf2 = wfp[128], wf3 = wfp[192];
            #pragma unroll
            for (int m = 0; m < MM; ++m) {
                float4 g = *(const float4*)&a12[m * A12LD + c];
                accf[m] += g.x * wf0 + g.y * wf1 + g.z * wf2 + g.w * wf3;
            }
        }
        float* part = &nbT[0][0];          // 1024 floats free; need 768
        if (w == 1) {
            #pragma unroll
            for (int m = 0; m < MM; ++m) part[m * 64 + j] = accf[m];
        }
        __syncthreads();
        if (w == 0) {
            #pragma unroll
            for (int m = 0; m < MM; ++m) {
                float v = accf[m] + part[m * 64 + j] + bf;
                pre[(bn * MM + m) * HAc + j] = v;
            }
        }
    }
}

// ---------------- K2: BN1 batch stats (sum, sumsq per column) over 49152 rows ----
__global__ __launch_bounds__(256) void k2_stats1(const float* __restrict__ pre,
                                                 float* __restrict__ stats1)
{
    const int t  = threadIdx.x;
    const int j  = t & 63;
    const int rg = t >> 6;
    const int base = blockIdx.x * 192 + rg;   // 256 blocks x 192 rows
    float s = 0.f, q = 0.f;
    for (int i = 0; i < 48; ++i) {
        float v = pre[(base + i * 4) * HAc + j];
        s += v; q += v * v;
    }
    __shared__ float red[2][4][64];
    red[0][rg][j] = s;
    red[1][rg][j] = q;
    __syncthreads();
    if (t < 64) {
        float S = red[0][0][j] + red[0][1][j] + red[0][2][j] + red[0][3][j];
        float Q = red[1][0][j] + red[1][1][j] + red[1][2][j] + red[1][3][j];
        atomicAdd(&stats1[j], S);
        atomicAdd(&stats1[64 + j], Q);
    }
}

// ---------------- K3: apply BN1 + relu + sum over M; accumulate BN2 stats ----
__global__ __launch_bounds__(256) void k3_bn1_sum(const float* __restrict__ pre,
                                                  const float* __restrict__ stats1,
                                                  const float* __restrict__ g1,
                                                  const float* __restrict__ b1,
                                                  float* __restrict__ tout,     // [B*N,64]
                                                  float* __restrict__ stats2)
{
    const int t  = threadIdx.x;
    const int j  = t & 63;
    const int rg = t >> 6;
    const float invR = 1.0f / 49152.0f;
    const float mean = stats1[j] * invR;
    const float var  = stats1[64 + j] * invR - mean * mean;
    const float rstd = rsqrtf(var + 1e-5f);
    const float ga = g1[j], be = b1[j];

    float s2 = 0.f, q2 = 0.f;
    for (int i = 0; i < 4; ++i) {
        const int bnrow = blockIdx.x * 16 + rg + i * 4;   // 256 blocks x 16 rows
        float s = 0.f;
        #pragma unroll
        for (int m = 0; m < MM; ++m) {
            float x = pre[(bnrow * MM + m) * HAc + j];
            float y = (x - mean) * rstd * ga + be;
            s += fmaxf(y, 0.f);
        }
        tout[bnrow * HAc + j] = s;
        s2 += s; q2 += s * s;
    }
    __shared__ float red[2][4][64];
    red[0][rg][j] = s2;
    red[1][rg][j] = q2;
    __syncthreads();
    if (t < 64) {
        float S = red[0][0][j] + red[0][1][j] + red[0][2][j] + red[0][3][j];
        float Q = red[1][0][j] + red[1][1][j] + red[1][2][j] + red[1][3][j];
        atomicAdd(&stats2[j], S);
        atomicAdd(&stats2[64 + j], Q);
    }
}

// ---------------- K4: apply BN2 + residual + relu -> out (float4) ----
__global__ __launch_bounds__(256) void k4_bn2_out(const float* __restrict__ tin,
                                                  const float* __restrict__ stats2,
                                                  const float* __restrict__ g2,
                                                  const float* __restrict__ b2,
                                                  const float* __restrict__ atom_emb,
                                                  float* __restrict__ out)
{
    const int i4 = blockIdx.x * 256 + threadIdx.x;   // 256 blocks -> 65536 float4 = 262144 floats
    const int j0 = (i4 & 15) * 4;                    // column of first component
    const float invR = 1.0f / 4096.0f;
    float4 tv = ((const float4*)tin)[i4];
    float4 ae = ((const float4*)atom_emb)[i4];
    float4 r;
    {
        float mean = stats2[j0] * invR;
        float var  = stats2[64 + j0] * invR - mean * mean;
        r.x = fmaxf(ae.x + (tv.x - mean) * rsqrtf(var + 1e-5f) * g2[j0] + b2[j0], 0.f);
    }
    {
        float mean = stats2[j0 + 1] * invR;
        float var  = stats2[64 + j0 + 1] * invR - mean * mean;
        r.y = fmaxf(ae.y + (tv.y - mean) * rsqrtf(var + 1e-5f) * g2[j0 + 1] + b2[j0 + 1], 0.f);
    }
    {
        float mean = stats2[j0 + 2] * invR;
        float var  = stats2[64 + j0 + 2] * invR - mean * mean;
        r.z = fmaxf(ae.z + (tv.z - mean) * rsqrtf(var + 1e-5f) * g2[j0 + 2] + b2[j0 + 2], 0.f);
    }
    {
        float mean = stats2[j0 + 3] * invR;
        float var  = stats2[64 + j0 + 3] * invR - mean * mean;
        r.w = fmaxf(ae.w + (tv.w - mean) * rsqrtf(var + 1e-5f) * g2[j0 + 3] + b2[j0 + 3], 0.f);
    }
    ((float4*)out)[i4] = r;
}

extern "C" void kernel_launch(void* const* d_in, const int* in_sizes, int n_in,
                              void* d_out, int out_size, void* d_ws, size_t ws_size,
                              hipStream_t stream)
{
    const float* atom_emb = (const float*)d_in[0];
    const float* nbr_emb  = (const float*)d_in[1];
    const float* atom_msk = (const float*)d_in[2];
    const float* W_full   = (const float*)d_in[3];
    const float* b_full   = (const float*)d_in[4];
    const float* W_final  = (const float*)d_in[5];
    const float* b_final  = (const float*)d_in[6];
    const float* bn1_g    = (const float*)d_in[7];
    const float* bn1_b    = (const float*)d_in[8];
    const float* bn2_g    = (const float*)d_in[9];
    const float* bn2_b    = (const float*)d_in[10];
    const int*   adj      = (const int*)d_in[11];
    float* out = (float*)d_out;

    float* ws     = (float*)d_ws;
    float* stats1 = ws;                    // 128 floats
    float* stats2 = ws + 128;              // 128 floats
    float* p12    = ws + 256;              // 4096*2048 = 8,388,608 floats
    float* pre    = p12 + 8388608;         // 49152*64  = 3,145,728 floats
    float* tout   = pre + 3145728;         // 4096*64   =   262,144 floats

    hipMemsetAsync(ws, 0, 256 * sizeof(float), stream);

    k0_p12<<<512, 256, 0, stream>>>(atom_emb, W_full, p12);
    k1_fused<<<BB * NN, 128, 0, stream>>>(nbr_emb, atom_msk, W_full, b_full,
                                          W_final, b_final, adj, p12, pre);
    k2_stats1<<<256, 256, 0, stream>>>(pre, stats1);
    k3_bn1_sum<<<256, 256, 0, stream>>>(pre, stats1, bn1_g, bn1_b, tout, stats2);
    k4_bn2_out<<<256, 256, 0, stream>>>(tout, stats2, bn2_g, bn2_b, atom_emb, out);
}

// Round 7
// 227.025 us; speedup vs baseline: 1.2677x; 1.2677x over previous
//
#include <hip/hip_runtime.h>

// Problem constants (fixed by the reference)
#define BB   16
#define NN   256
#define MM   12
#define HAc  64
#define Hh   4

typedef __attribute__((ext_vector_type(8))) short bf16x8;   // 8 bf16 = 4 VGPRs
typedef __attribute__((ext_vector_type(4))) float f32x4;

__device__ __forceinline__ unsigned short bf16_rne(float x) {
    unsigned u = __builtin_bit_cast(unsigned, x);
    unsigned r = u + 0x7fffu + ((u >> 16) & 1u);
    return (unsigned short)(r >> 16);
}
__device__ __forceinline__ float bf16f(unsigned short h) {
    unsigned u = ((unsigned)h) << 16;
    return __builtin_bit_cast(float, u);
}
// split 8 fp32 into hi/lo bf16 fragments (bf16x3 decomposition: a ~= hi + lo)
__device__ __forceinline__ void split8(float4 a, float4 b, bf16x8& hi, bf16x8& lo) {
    float v[8] = {a.x, a.y, a.z, a.w, b.x, b.y, b.z, b.w};
    #pragma unroll
    for (int j = 0; j < 8; ++j) {
        unsigned short h = bf16_rne(v[j]);
        hi[j] = (short)h;
        lo[j] = (short)bf16_rne(v[j] - bf16f(h));
    }
}

// ---------------- k0_prep ----------------
// blocks 0..511:   P1b = atom_emb@W1 + b_full ; P2 = atom_emb@W2   (fp32 VALU GEMM)
// blocks 512..575: pack W3 (W_full rows 128..191) -> bf16 hi/lo, MFMA-B-fragment order
// blocks 576..591: pack W_final -> bf16 hi/lo, MFMA-B-fragment order
__global__ __launch_bounds__(256) void k0_prep(
    const float* __restrict__ atom_emb,   // [4096,64]
    const float* __restrict__ W_full,     // [192,1024]
    const float* __restrict__ b_full,     // [1024]
    const float* __restrict__ W_final,    // [256,64]
    float* __restrict__ p1b,              // [4096,1024]
    float* __restrict__ p2,               // [4096,1024]
    short* __restrict__ w3pk,             // [64nt][2ks][2p][64lane][8]
    short* __restrict__ wfpk)             // [4nt][8ks][2p][64lane][8]
{
    const int t = threadIdx.x;
    if (blockIdx.x < 512) {
        __shared__ float sA[8][64];
        const int r0 = blockIdx.x * 8;
        for (int e = t; e < 512; e += 256) sA[e >> 6][e & 63] = atom_emb[r0 * 64 + e];
        __syncthreads();

        const float4* W4 = (const float4*)W_full;   // [192][256] float4
        float4 acc0[8], acc1[8];
        #pragma unroll
        for (int r = 0; r < 8; ++r) {
            acc0[r] = make_float4(0.f, 0.f, 0.f, 0.f);
            acc1[r] = make_float4(0.f, 0.f, 0.f, 0.f);
        }
        for (int k = 0; k < 64; ++k) {
            float4 w0 = W4[k * 256 + t];            // W1 row k
            float4 w1 = W4[(k + 64) * 256 + t];     // W2 row k
            #pragma unroll
            for (int r = 0; r < 8; ++r) {
                float a = sA[r][k];
                acc0[r].x += a * w0.x; acc0[r].y += a * w0.y; acc0[r].z += a * w0.z; acc0[r].w += a * w0.w;
                acc1[r].x += a * w1.x; acc1[r].y += a * w1.y; acc1[r].z += a * w1.z; acc1[r].w += a * w1.w;
            }
        }
        float4 bb = ((const float4*)b_full)[t];
        float4* P1 = (float4*)p1b;
        float4* P2 = (float4*)p2;
        #pragma unroll
        for (int r = 0; r < 8; ++r) {
            float4 v = acc0[r];
            v.x += bb.x; v.y += bb.y; v.z += bb.z; v.w += bb.w;
            P1[(r0 + r) * 256 + t] = v;
            P2[(r0 + r) * 256 + t] = acc1[r];
        }
    } else {
        const int pb = blockIdx.x - 512;
        const int gid = pb * 256 + t;
        if (pb < 64) {
            // W3 pack: gid in [0,16384)
            const int lane = gid & 63;
            const int rest = gid >> 6;          // 0..255
            const int p  = rest & 1;
            const int ks = (rest >> 1) & 1;
            const int nt = rest >> 2;           // 0..63
            const int kb = ks * 32 + (lane >> 4) * 8;
            const int n  = nt * 16 + (lane & 15);
            bf16x8 o;
            #pragma unroll
            for (int j = 0; j < 8; ++j) {
                float v = W_full[(128 + kb + j) * 1024 + n];
                unsigned short h = bf16_rne(v);
                o[j] = p ? (short)bf16_rne(v - bf16f(h)) : (short)h;
            }
            *((bf16x8*)(w3pk + ((nt * 4 + ks * 2 + p) * 64 + lane) * 8)) = o;
        } else {
            // W_final pack: idx in [0,4096)
            const int idx = gid - 16384;
            const int lane = idx & 63;
            const int rest = idx >> 6;          // 0..63
            const int p  = rest & 1;
            const int ks = (rest >> 1) & 7;
            const int nt = rest >> 4;           // 0..3
            const int kb = ks * 32 + (lane >> 4) * 8;
            const int n  = nt * 16 + (lane & 15);
            bf16x8 o;
            #pragma unroll
            for (int j = 0; j < 8; ++j) {
                float v = W_final[(kb + j) * 64 + n];
                unsigned short h = bf16_rne(v);
                o[j] = p ? (short)bf16_rne(v - bf16f(h)) : (short)h;
            }
            *((bf16x8*)(wfpk + ((nt * 8 + ks) * 2 + p) * 512 + lane * 8)) = o;
        }
    }
}

// ---------------- k1: fused bond-GEMM(MFMA) + attention(MFMA scores) +
// gating + final GEMM(MFMA). One block per (b,n) atom, 256 threads (4 waves).
// tg layout (fp32, rows m=0..11): cols 0-255 gate, 256-511 core, 512-767 a1, 768-1023 a2.
// After phase D, a1 region is reused as bf16 gc planes (hi @ float-col 512, lo @ 640).
__global__ __launch_bounds__(256) void k1_fused(
    const float* __restrict__ nbr_emb,    // [B,N,M,64]
    const float* __restrict__ atom_mask,  // [B,N,1]
    const float* __restrict__ p1b,        // [4096,1024]
    const float* __restrict__ p2,         // [4096,1024]
    const short* __restrict__ w3pk,
    const short* __restrict__ wfpk,
    const float* __restrict__ b_final,    // [64]
    const int*   __restrict__ adj,        // [B,N,M]
    float* __restrict__ pre)              // out: [B,N,M,64] pre-BN1
{
    __shared__ __align__(16) float tg[12][1028];     // 49.3 KB (1028: 16B-aligned rows, 4-bank skew)
    __shared__ float scr[Hh][MM][MM];                // 2.3 KB

    const int bn   = blockIdx.x;
    const int b    = bn >> 8;
    const int t    = threadIdx.x;
    const int w    = t >> 6;        // wave 0..3
    const int lane = t & 63;
    const int lr   = lane & 15;     // row-in-tile (A/B operand) / col-in-tile (C/D)
    const int kg   = lane >> 4;     // 0..3
    const float mask = atom_mask[bn];

    // ---- A-fragments for phase B: nbr_emb rows, bf16 hi/lo, 2 K-steps ----
    // A-frag layout: lane holds A[lane&15][ (lane>>4)*8 + j ]
    bf16x8 nAhi[2], nAlo[2];
    #pragma unroll
    for (int ks = 0; ks < 2; ++ks) {
        float4 v0 = make_float4(0.f, 0.f, 0.f, 0.f), v1 = v0;
        if (lr < 12) {
            const float4* np = (const float4*)(nbr_emb + bn * 768 + lr * 64 + ks * 32 + kg * 8);
            v0 = np[0]; v1 = np[1];
        }
        split8(v0, v1, nAhi[ks], nAlo[ks]);
    }

    // neighbor rows for this lane's 4 C-rows (m = kg*4 + r)
    int nr[4];
    #pragma unroll
    for (int r = 0; r < 4; ++r) {
        int m = kg * 4 + r;
        nr[r] = (m < 12) ? (b * NN + adj[bn * MM + m]) : 0;
    }

    // ---- Phase B: tg = P1b + mask*P2[nbr] + nbr_emb @ W3  (split-bf16 MFMA) ----
    {
        const bf16x8* W3P = (const bf16x8*)w3pk;
        #pragma unroll 4
        for (int i = 0; i < 16; ++i) {
            const int nt = w * 16 + i;
            const int n  = nt * 16 + lr;
            bf16x8 B0h = W3P[(nt * 4 + 0) * 64 + lane];
            bf16x8 B0l = W3P[(nt * 4 + 1) * 64 + lane];
            bf16x8 B1h = W3P[(nt * 4 + 2) * 64 + lane];
            bf16x8 B1l = W3P[(nt * 4 + 3) * 64 + lane];
            const float p1v = p1b[bn * 1024 + n];
            f32x4 acc;
            #pragma unroll
            for (int r = 0; r < 4; ++r) {
                float pv = (kg * 4 + r < 12) ? p2[nr[r] * 1024 + n] : 0.f;
                acc[r] = p1v + mask * pv;
            }
            acc = __builtin_amdgcn_mfma_f32_16x16x32_bf16(nAhi[0], B0h, acc, 0, 0, 0);
            acc = __builtin_amdgcn_mfma_f32_16x16x32_bf16(nAhi[0], B0l, acc, 0, 0, 0);
            acc = __builtin_amdgcn_mfma_f32_16x16x32_bf16(nAlo[0], B0h, acc, 0, 0, 0);
            acc = __builtin_amdgcn_mfma_f32_16x16x32_bf16(nAhi[1], B1h, acc, 0, 0, 0);
            acc = __builtin_amdgcn_mfma_f32_16x16x32_bf16(nAhi[1], B1l, acc, 0, 0, 0);
            acc = __builtin_amdgcn_mfma_f32_16x16x32_bf16(nAlo[1], B1h, acc, 0, 0, 0);
            if (kg < 3) {   // D rows m = kg*4+r in [0,12)
                #pragma unroll
                for (int r = 0; r < 4; ++r) tg[kg * 4 + r][n] = acc[r];
            }
        }
    }
    __syncthreads();

    // ---- Phase C: scores via MFMA, wave w = head h ----
    {
        const int h = w;
        bf16x8 a1h[2], a1l[2], a2h[2], a2l[2];
        #pragma unroll
        for (int ks = 0; ks < 2; ++ks) {
            float4 x0 = make_float4(0.f, 0.f, 0.f, 0.f), x1 = x0, y0 = x0, y1 = x0;
            if (lr < 12) {
                const float4* pa = (const float4*)&tg[lr][512 + h * 64 + ks * 32 + kg * 8];
                x0 = pa[0]; x1 = pa[1];
                const float4* pb = (const float4*)&tg[lr][768 + h * 64 + ks * 32 + kg * 8];
                y0 = pb[0]; y1 = pb[1];
            }
            split8(x0, x1, a1h[ks], a1l[ks]);
            split8(y0, y1, a2h[ks], a2l[ks]);
        }
        f32x4 sc = {0.f, 0.f, 0.f, 0.f};
        sc = __builtin_amdgcn_mfma_f32_16x16x32_bf16(a1h[0], a2h[0], sc, 0, 0, 0);
        sc = __builtin_amdgcn_mfma_f32_16x16x32_bf16(a1h[0], a2l[0], sc, 0, 0, 0);
        sc = __builtin_amdgcn_mfma_f32_16x16x32_bf16(a1l[0], a2h[0], sc, 0, 0, 0);
        sc = __builtin_amdgcn_mfma_f32_16x16x32_bf16(a1h[1], a2h[1], sc, 0, 0, 0);
        sc = __builtin_amdgcn_mfma_f32_16x16x32_bf16(a1h[1], a2l[1], sc, 0, 0, 0);
        sc = __builtin_amdgcn_mfma_f32_16x16x32_bf16(a1l[1], a2h[1], sc, 0, 0, 0);
        const float bias = (1.0f - mask) * (-10000.0f);
        if (kg < 3 && lr < 12) {
            #pragma unroll
            for (int r = 0; r < 4; ++r)
                scr[h][kg * 4 + r][lr] = 0.5f * sc[r] + bias;
        }
    }
    __syncthreads();

    // ---- softmax over k: one thread per (h,m) row ----
    if (t < Hh * MM) {
        float* row = &scr[0][0][0] + t * MM;
        float mx = row[0];
        #pragma unroll
        for (int k = 1; k < MM; ++k) mx = fmaxf(mx, row[k]);
        float e[MM];
        float sum = 0.f;
        #pragma unroll
        for (int k = 0; k < MM; ++k) { e[k] = __expf(row[k] - mx); sum += e[k]; }
        float inv = 1.0f / sum;
        #pragma unroll
        for (int k = 0; k < MM; ++k) row[k] = e[k] * inv;
    }
    __syncthreads();

    // ---- Phase D: ctx + relu + sigmoid(gate) -> gc as bf16 hi/lo planes ----
    {
        const int c = t;            // 0..255
        const int h = c >> 6;       // wave-uniform
        float cv[MM];
        #pragma unroll
        for (int k = 0; k < MM; ++k) cv[k] = tg[k][256 + c];
        #pragma unroll
        for (int m = 0; m < MM; ++m) {
            float s = 0.f;
            #pragma unroll
            for (int k = 0; k < MM; ++k) s += scr[h][m][k] * cv[k];
            float gv = tg[m][c];
            float gt = 1.0f / (1.0f + __expf(-gv));
            float gc = gt * fmaxf(s, 0.f);
            unsigned short hh = bf16_rne(gc);
            unsigned short ll = bf16_rne(gc - bf16f(hh));
            short* pm = (short*)&tg[m][512];      // hi plane: shorts [0,256); lo plane: [256,512)
            pm[c]       = (short)hh;
            pm[256 + c] = (short)ll;
        }
    }
    __syncthreads();

    // ---- Phase E: summed = gc @ W_final + b_final  (split-bf16 MFMA, wave w -> col tile) ----
    {
        const bf16x8* WFP = (const bf16x8*)wfpk;
        f32x4 acc = {0.f, 0.f, 0.f, 0.f};
        #pragma unroll 2
        for (int ks = 0; ks < 8; ++ks) {
            bf16x8 Ah = {0,0,0,0,0,0,0,0}, Al = Ah;
            if (lr < 12) {
                const short* pm = (const short*)&tg[lr][512];
                Ah = *(const bf16x8*)(pm + ks * 32 + kg * 8);
                Al = *(const bf16x8*)(pm + 256 + ks * 32 + kg * 8);
            }
            bf16x8 Bh = WFP[(w * 8 + ks) * 128 + lane];        // ((nt*8+ks)*2+0)*64
            bf16x8 Bl = WFP[(w * 8 + ks) * 128 + 64 + lane];   // ((nt*8+ks)*2+1)*64
            acc = __builtin_amdgcn_mfma_f32_16x16x32_bf16(Ah, Bh, acc, 0, 0, 0);
            acc = __builtin_amdgcn_mfma_f32_16x16x32_bf16(Ah, Bl, acc, 0, 0, 0);
            acc = __builtin_amdgcn_mfma_f32_16x16x32_bf16(Al, Bh, acc, 0, 0, 0);
        }
        const int n = w * 16 + lr;
        const float bf = b_final[n];
        if (kg < 3) {
            #pragma unroll
            for (int r = 0; r < 4; ++r)
                pre[(bn * MM + kg * 4 + r) * HAc + n] = acc[r] + bf;
        }
    }
}

// ---------------- K2: BN1 batch stats over 49152 rows ----------------
__global__ __launch_bounds__(256) void k2_stats1(const float* __restrict__ pre,
                                                 float* __restrict__ stats1)
{
    const int t  = threadIdx.x;
    const int j  = t & 63;
    const int rg = t >> 6;
    const int base = blockIdx.x * 192 + rg;
    float s = 0.f, q = 0.f;
    for (int i = 0; i < 48; ++i) {
        float v = pre[(base + i * 4) * HAc + j];
        s += v; q += v * v;
    }
    __shared__ float red[2][4][64];
    red[0][rg][j] = s;
    red[1][rg][j] = q;
    __syncthreads();
    if (t < 64) {
        float S = red[0][0][j] + red[0][1][j] + red[0][2][j] + red[0][3][j];
        float Q = red[1][0][j] + red[1][1][j] + red[1][2][j] + red[1][3][j];
        atomicAdd(&stats1[j], S);
        atomicAdd(&stats1[64 + j], Q);
    }
}

// ---------------- K3: BN1 apply + relu + sum over M; BN2 stats ----------------
__global__ __launch_bounds__(256) void k3_bn1_sum(const float* __restrict__ pre,
                                                  const float* __restrict__ stats1,
                                                  const float* __restrict__ g1,
                                                  const float* __restrict__ b1,
                                                  float* __restrict__ tout,     // [B*N,64]
                                                  float* __restrict__ stats2)
{
    const int t  = threadIdx.x;
    const int j  = t & 63;
    const int rg = t >> 6;
    const float invR = 1.0f / 49152.0f;
    const float mean = stats1[j] * invR;
    const float var  = stats1[64 + j] * invR - mean * mean;
    const float rstd = rsqrtf(var + 1e-5f);
    const float ga = g1[j], be = b1[j];

    float s2 = 0.f, q2 = 0.f;
    for (int i = 0; i < 4; ++i) {
        const int bnrow = blockIdx.x * 16 + rg + i * 4;
        float s = 0.f;
        #pragma unroll
        for (int m = 0; m < MM; ++m) {
            float x = pre[(bnrow * MM + m) * HAc + j];
            float y = (x - mean) * rstd * ga + be;
            s += fmaxf(y, 0.f);
        }
        tout[bnrow * HAc + j] = s;
        s2 += s; q2 += s * s;
    }
    __shared__ float red[2][4][64];
    red[0][rg][j] = s2;
    red[1][rg][j] = q2;
    __syncthreads();
    if (t < 64) {
        float S = red[0][0][j] + red[0][1][j] + red[0][2][j] + red[0][3][j];
        float Q = red[1][0][j] + red[1][1][j] + red[1][2][j] + red[1][3][j];
        atomicAdd(&stats2[j], S);
        atomicAdd(&stats2[64 + j], Q);
    }
}

// ---------------- K4: BN2 apply + residual + relu -> out (float4) ----------------
__global__ __launch_bounds__(256) void k4_bn2_out(const float* __restrict__ tin,
                                                  const float* __restrict__ stats2,
                                                  const float* __restrict__ g2,
                                                  const float* __restrict__ b2,
                                                  const float* __restrict__ atom_emb,
                                                  float* __restrict__ out)
{
    const int i4 = blockIdx.x * 256 + threadIdx.x;   // 65536 float4
    const int j0 = (i4 & 15) * 4;
    const float invR = 1.0f / 4096.0f;
    float4 tv = ((const float4*)tin)[i4];
    float4 ae = ((const float4*)atom_emb)[i4];
    float4 r;
    {
        float mean = stats2[j0] * invR;
        float var  = stats2[64 + j0] * invR - mean * mean;
        r.x = fmaxf(ae.x + (tv.x - mean) * rsqrtf(var + 1e-5f) * g2[j0] + b2[j0], 0.f);
    }
    {
        float mean = stats2[j0 + 1] * invR;
        float var  = stats2[64 + j0 + 1] * invR - mean * mean;
        r.y = fmaxf(ae.y + (tv.y - mean) * rsqrtf(var + 1e-5f) * g2[j0 + 1] + b2[j0 + 1], 0.f);
    }
    {
        float mean = stats2[j0 + 2] * invR;
        float var  = stats2[64 + j0 + 2] * invR - mean * mean;
        r.z = fmaxf(ae.z + (tv.z - mean) * rsqrtf(var + 1e-5f) * g2[j0 + 2] + b2[j0 + 2], 0.f);
    }
    {
        float mean = stats2[j0 + 3] * invR;
        float var  = stats2[64 + j0 + 3] * invR - mean * mean;
        r.w = fmaxf(ae.w + (tv.w - mean) * rsqrtf(var + 1e-5f) * g2[j0 + 3] + b2[j0 + 3], 0.f);
    }
    ((float4*)out)[i4] = r;
}

extern "C" void kernel_launch(void* const* d_in, const int* in_sizes, int n_in,
                              void* d_out, int out_size, void* d_ws, size_t ws_size,
                              hipStream_t stream)
{
    const float* atom_emb = (const float*)d_in[0];
    const float* nbr_emb  = (const float*)d_in[1];
    const float* atom_msk = (const float*)d_in[2];
    const float* W_full   = (const float*)d_in[3];
    const float* b_full   = (const float*)d_in[4];
    const float* W_final  = (const float*)d_in[5];
    const float* b_final  = (const float*)d_in[6];
    const float* bn1_g    = (const float*)d_in[7];
    const float* bn1_b    = (const float*)d_in[8];
    const float* bn2_g    = (const float*)d_in[9];
    const float* bn2_b    = (const float*)d_in[10];
    const int*   adj      = (const int*)d_in[11];
    float* out = (float*)d_out;

    float* ws     = (float*)d_ws;
    float* stats1 = ws;                    // 128
    float* stats2 = ws + 128;              // 128
    float* p1b    = ws + 256;              // 4096*1024 = 4,194,304
    float* p2     = p1b + 4194304;         // 4,194,304
    float* pre    = p2 + 4194304;          // 49152*64 = 3,145,728
    short* w3pk   = (short*)(pre + 3145728);   // 131,072 shorts
    short* wfpk   = w3pk + 131072;             //  32,768 shorts
    float* tout   = p1b;                   // alias: p1b dead after k1; tout needs 262,144 floats

    hipMemsetAsync(ws, 0, 256 * sizeof(float), stream);

    k0_prep<<<592, 256, 0, stream>>>(atom_emb, W_full, b_full, W_final, p1b, p2, w3pk, wfpk);
    k1_fused<<<BB * NN, 256, 0, stream>>>(nbr_emb, atom_msk, p1b, p2, w3pk, wfpk,
                                          b_final, adj, pre);
    k2_stats1<<<256, 256, 0, stream>>>(pre, stats1);
    k3_bn1_sum<<<256, 256, 0, stream>>>(pre, stats1, bn1_g, bn1_b, tout, stats2);
    k4_bn2_out<<<256, 256, 0, stream>>>(tout, stats2, bn2_g, bn2_b, atom_emb, out);
}

// Round 8
// 226.269 us; speedup vs baseline: 1.2719x; 1.0033x over previous
//
#include <hip/hip_runtime.h>

// Problem constants (fixed by the reference)
#define BB   16
#define NN   256
#define MM   12
#define HAc  64
#define Hh   4

#define PLD  264   // plane row stride in shorts (528B, 16B-aligned, floor-rate b128 reads)
#define TGLD 521   // tg row stride in floats (odd -> de-conflicted scalar writes/reads)

typedef __attribute__((ext_vector_type(8))) short bf16x8;   // 8 bf16 = 4 VGPRs
typedef __attribute__((ext_vector_type(4))) float f32x4;

__device__ __forceinline__ unsigned short bf16_rne(float x) {
    unsigned u = __builtin_bit_cast(unsigned, x);
    unsigned r = u + 0x7fffu + ((u >> 16) & 1u);
    return (unsigned short)(r >> 16);
}
__device__ __forceinline__ float bf16f(unsigned short h) {
    unsigned u = ((unsigned)h) << 16;
    return __builtin_bit_cast(float, u);
}
// split 8 fp32 into hi/lo bf16 fragments (bf16x3 decomposition: a ~= hi + lo)
__device__ __forceinline__ void split8(float4 a, float4 b, bf16x8& hi, bf16x8& lo) {
    float v[8] = {a.x, a.y, a.z, a.w, b.x, b.y, b.z, b.w};
    #pragma unroll
    for (int j = 0; j < 8; ++j) {
        unsigned short h = bf16_rne(v[j]);
        hi[j] = (short)h;
        lo[j] = (short)bf16_rne(v[j] - bf16f(h));
    }
}

// ---------------- k0a: pack all weights to MFMA-B-fragment bf16 hi/lo ----------------
// blocks 0..127:   W12 = [W1 | W2] (W_full rows 0..127) -> w12pk [128nt][2ks][2p][64lane][8]
// blocks 128..191: W3 (W_full rows 128..191)            -> w3pk  [64nt][2ks][2p][64lane][8]
// blocks 192..207: W_final                              -> wfpk  [4nt][8ks][2p][64lane][8]
__global__ __launch_bounds__(256) void k0a_pack(
    const float* __restrict__ W_full,     // [192,1024]
    const float* __restrict__ W_final,    // [256,64]
    short* __restrict__ w12pk,
    short* __restrict__ w3pk,
    short* __restrict__ wfpk)
{
    const int t = threadIdx.x;
    if (blockIdx.x < 128) {
        const int gid  = blockIdx.x * 256 + t;     // [0,32768)
        const int lane = gid & 63;
        const int rest = gid >> 6;                 // 0..511
        const int p  = rest & 1;
        const int ks = (rest >> 1) & 1;
        const int nt = rest >> 2;                  // 0..127
        const int rbase = (nt >= 64 ? 64 : 0) + ks * 32 + (lane >> 4) * 8;
        const int n  = (nt & 63) * 16 + (lane & 15);
        bf16x8 o;
        #pragma unroll
        for (int j = 0; j < 8; ++j) {
            float v = W_full[(rbase + j) * 1024 + n];
            unsigned short h = bf16_rne(v);
            o[j] = p ? (short)bf16_rne(v - bf16f(h)) : (short)h;
        }
        *((bf16x8*)(w12pk + ((nt * 4 + ks * 2 + p) * 64 + lane) * 8)) = o;
    } else if (blockIdx.x < 192) {
        const int gid  = (blockIdx.x - 128) * 256 + t;   // [0,16384)
        const int lane = gid & 63;
        const int rest = gid >> 6;                 // 0..255
        const int p  = rest & 1;
        const int ks = (rest >> 1) & 1;
        const int nt = rest >> 2;                  // 0..63
        const int kb = ks * 32 + (lane >> 4) * 8;
        const int n  = nt * 16 + (lane & 15);
        bf16x8 o;
        #pragma unroll
        for (int j = 0; j < 8; ++j) {
            float v = W_full[(128 + kb + j) * 1024 + n];
            unsigned short h = bf16_rne(v);
            o[j] = p ? (short)bf16_rne(v - bf16f(h)) : (short)h;
        }
        *((bf16x8*)(w3pk + ((nt * 4 + ks * 2 + p) * 64 + lane) * 8)) = o;
    } else {
        const int idx  = (blockIdx.x - 192) * 256 + t;   // [0,4096)
        const int lane = idx & 63;
        const int rest = idx >> 6;                 // 0..63
        const int p  = rest & 1;
        const int ks = (rest >> 1) & 7;
        const int nt = rest >> 4;                  // 0..3
        const int kb = ks * 32 + (lane >> 4) * 8;
        const int n  = nt * 16 + (lane & 15);
        bf16x8 o;
        #pragma unroll
        for (int j = 0; j < 8; ++j) {
            float v = W_final[(kb + j) * 64 + n];
            unsigned short h = bf16_rne(v);
            o[j] = p ? (short)bf16_rne(v - bf16f(h)) : (short)h;
        }
        *((bf16x8*)(wfpk + ((nt * 8 + ks) * 2 + p) * 512 + lane * 8)) = o;
    }
}

// ---------------- k0b: P1b = atom_emb@W1 + b_full ; P2 = atom_emb@W2 (split-bf16 MFMA) --
// 256 blocks x 16 atom rows; 4 waves, wave w covers n-tiles w*32..w*32+31 of 128.
__global__ __launch_bounds__(256) void k0b_p12(
    const float* __restrict__ atom_emb,   // [4096,64]
    const float* __restrict__ b_full,     // [1024]
    const short* __restrict__ w12pk,
    float* __restrict__ p1b,              // [4096,1024]
    float* __restrict__ p2)               // [4096,1024]
{
    const int r0   = blockIdx.x * 16;
    const int t    = threadIdx.x;
    const int w    = t >> 6;
    const int lane = t & 63;
    const int lr   = lane & 15;
    const int kg   = lane >> 4;

    // A-fragments: rows r0+lr (all valid), K=64 in 2 chunks
    bf16x8 aAh[2], aAl[2];
    #pragma unroll
    for (int ks = 0; ks < 2; ++ks) {
        const float4* ap = (const float4*)(atom_emb + (r0 + lr) * 64 + ks * 32 + kg * 8);
        split8(ap[0], ap[1], aAh[ks], aAl[ks]);
    }

    const bf16x8* W12P = (const bf16x8*)w12pk;
    #pragma unroll 4
    for (int i = 0; i < 32; ++i) {
        const int nt = w * 32 + i;
        bf16x8 Bh0 = W12P[(nt * 4 + 0) * 64 + lane];
        bf16x8 Bl0 = W12P[(nt * 4 + 1) * 64 + lane];
        bf16x8 Bh1 = W12P[(nt * 4 + 2) * 64 + lane];
        bf16x8 Bl1 = W12P[(nt * 4 + 3) * 64 + lane];
        const int n = (nt & 63) * 16 + lr;
        f32x4 acc;
        if (nt < 64) {
            float bv = b_full[n];
            acc[0] = bv; acc[1] = bv; acc[2] = bv; acc[3] = bv;
        } else {
            acc[0] = 0.f; acc[1] = 0.f; acc[2] = 0.f; acc[3] = 0.f;
        }
        acc = __builtin_amdgcn_mfma_f32_16x16x32_bf16(aAh[0], Bh0, acc, 0, 0, 0);
        acc = __builtin_amdgcn_mfma_f32_16x16x32_bf16(aAh[0], Bl0, acc, 0, 0, 0);
        acc = __builtin_amdgcn_mfma_f32_16x16x32_bf16(aAl[0], Bh0, acc, 0, 0, 0);
        acc = __builtin_amdgcn_mfma_f32_16x16x32_bf16(aAh[1], Bh1, acc, 0, 0, 0);
        acc = __builtin_amdgcn_mfma_f32_16x16x32_bf16(aAh[1], Bl1, acc, 0, 0, 0);
        acc = __builtin_amdgcn_mfma_f32_16x16x32_bf16(aAl[1], Bh1, acc, 0, 0, 0);
        float* dst = (nt < 64) ? p1b : p2;
        #pragma unroll
        for (int r = 0; r < 4; ++r)
            dst[(r0 + kg * 4 + r) * 1024 + n] = acc[r];
    }
}

// ---------------- k1: fused bond-GEMM(MFMA) + attention(MFMA) + gating + final GEMM ----
// One block per (b,n) atom, 256 threads (4 waves). Wave w owns column chunk w:
// w0 gate (tg cols 0-255 fp32), w1 core (tg 256-511 fp32), w2 a1 -> bf16 planes,
// w3 a2 -> bf16 planes. After phase D, a1 planes are reused as gc hi/lo planes.
__global__ __launch_bounds__(256) void k1_fused(
    const float* __restrict__ nbr_emb,    // [B,N,M,64]
    const float* __restrict__ atom_mask,  // [B,N,1]
    const float* __restrict__ p1b,        // [4096,1024]
    const float* __restrict__ p2,         // [4096,1024]
    const short* __restrict__ w3pk,
    const short* __restrict__ wfpk,
    const float* __restrict__ b_final,    // [64]
    const int*   __restrict__ adj,        // [B,N,M]
    float* __restrict__ pre)              // out: [B,N,M,64] pre-BN1
{
    __shared__ __align__(16) float tg[12][TGLD];       // 25.0 KB: gate cols 0-255, core 256-511
    __shared__ __align__(16) short a1hi[12 * PLD];     // 6.2 KB each
    __shared__ __align__(16) short a1lo[12 * PLD];
    __shared__ __align__(16) short a2hi[12 * PLD];
    __shared__ __align__(16) short a2lo[12 * PLD];
    __shared__ float scr[Hh][MM][MM];                  // 2.25 KB

    const int bn   = blockIdx.x;
    const int b    = bn >> 8;
    const int t    = threadIdx.x;
    const int w    = t >> 6;        // wave 0..3 = column chunk
    const int lane = t & 63;
    const int lr   = lane & 15;
    const int kg   = lane >> 4;
    const float mask = atom_mask[bn];

    // ---- A-fragments for phase B: nbr_emb rows, bf16 hi/lo, 2 K-steps ----
    bf16x8 nAhi[2], nAlo[2];
    #pragma unroll
    for (int ks = 0; ks < 2; ++ks) {
        float4 v0 = make_float4(0.f, 0.f, 0.f, 0.f), v1 = v0;
        if (lr < 12) {
            const float4* np = (const float4*)(nbr_emb + bn * 768 + lr * 64 + ks * 32 + kg * 8);
            v0 = np[0]; v1 = np[1];
        }
        split8(v0, v1, nAhi[ks], nAlo[ks]);
    }

    // neighbor rows for this lane's 4 C-rows (m = kg*4 + r)
    int nr[4];
    #pragma unroll
    for (int r = 0; r < 4; ++r) {
        int m = kg * 4 + r;
        nr[r] = (m < 12) ? (b * NN + adj[bn * MM + m]) : 0;
    }

    // ---- Phase B: tg/planes = P1b + mask*P2[nbr] + nbr_emb @ W3 (split-bf16 MFMA) ----
    {
        const bf16x8* W3P = (const bf16x8*)w3pk;
        #pragma unroll 4
        for (int i = 0; i < 16; ++i) {
            const int nt = w * 16 + i;
            const int n  = nt * 16 + lr;
            bf16x8 B0h = W3P[(nt * 4 + 0) * 64 + lane];
            bf16x8 B0l = W3P[(nt * 4 + 1) * 64 + lane];
            bf16x8 B1h = W3P[(nt * 4 + 2) * 64 + lane];
            bf16x8 B1l = W3P[(nt * 4 + 3) * 64 + lane];
            const float p1v = p1b[bn * 1024 + n];
            f32x4 acc;
            #pragma unroll
            for (int r = 0; r < 4; ++r) {
                float pv = (kg * 4 + r < 12) ? p2[nr[r] * 1024 + n] : 0.f;
                acc[r] = p1v + mask * pv;
            }
            acc = __builtin_amdgcn_mfma_f32_16x16x32_bf16(nAhi[0], B0h, acc, 0, 0, 0);
            acc = __builtin_amdgcn_mfma_f32_16x16x32_bf16(nAhi[0], B0l, acc, 0, 0, 0);
            acc = __builtin_amdgcn_mfma_f32_16x16x32_bf16(nAlo[0], B0h, acc, 0, 0, 0);
            acc = __builtin_amdgcn_mfma_f32_16x16x32_bf16(nAhi[1], B1h, acc, 0, 0, 0);
            acc = __builtin_amdgcn_mfma_f32_16x16x32_bf16(nAhi[1], B1l, acc, 0, 0, 0);
            acc = __builtin_amdgcn_mfma_f32_16x16x32_bf16(nAlo[1], B1h, acc, 0, 0, 0);
            if (kg < 3) {
                if (w < 2) {
                    // gate/core: fp32 into tg (cols n in [0,512))
                    #pragma unroll
                    for (int r = 0; r < 4; ++r) tg[kg * 4 + r][n] = acc[r];
                } else {
                    // a1/a2: split to bf16 hi/lo planes, local col = i*16+lr
                    const int cl = i * 16 + lr;
                    short* phi = (w == 2) ? a1hi : a2hi;
                    short* plo = (w == 2) ? a1lo : a2lo;
                    #pragma unroll
                    for (int r = 0; r < 4; ++r) {
                        const int row = kg * 4 + r;
                        unsigned short h = bf16_rne(acc[r]);
                        phi[row * PLD + cl] = (short)h;
                        plo[row * PLD + cl] = (short)bf16_rne(acc[r] - bf16f(h));
                    }
                }
            }
        }
    }
    __syncthreads();

    // ---- Phase C: scores via MFMA, wave w = head h; frags read pre-split ----
    {
        const int h = w;
        f32x4 sc = {0.f, 0.f, 0.f, 0.f};
        #pragma unroll
        for (int ks = 0; ks < 2; ++ks) {
            bf16x8 x1h = {0,0,0,0,0,0,0,0}, x1l = x1h, x2h = x1h, x2l = x1h;
            if (lr < 12) {
                const int col = h * 64 + ks * 32 + kg * 8;
                x1h = *(const bf16x8*)&a1hi[lr * PLD + col];
                x1l = *(const bf16x8*)&a1lo[lr * PLD + col];
                x2h = *(const bf16x8*)&a2hi[lr * PLD + col];
                x2l = *(const bf16x8*)&a2lo[lr * PLD + col];
            }
            sc = __builtin_amdgcn_mfma_f32_16x16x32_bf16(x1h, x2h, sc, 0, 0, 0);
            sc = __builtin_amdgcn_mfma_f32_16x16x32_bf16(x1h, x2l, sc, 0, 0, 0);
            sc = __builtin_amdgcn_mfma_f32_16x16x32_bf16(x1l, x2h, sc, 0, 0, 0);
        }
        const float bias = (1.0f - mask) * (-10000.0f);
        if (kg < 3 && lr < 12) {
            #pragma unroll
            for (int r = 0; r < 4; ++r)
                scr[h][kg * 4 + r][lr] = 0.5f * sc[r] + bias;
        }
    }
    __syncthreads();

    // ---- softmax over k: one thread per (h,m) row ----
    if (t < Hh * MM) {
        float* row = &scr[0][0][0] + t * MM;
        float mx = row[0];
        #pragma unroll
        for (int k = 1; k < MM; ++k) mx = fmaxf(mx, row[k]);
        float e[MM];
        float sum = 0.f;
        #pragma unroll
        for (int k = 0; k < MM; ++k) { e[k] = __expf(row[k] - mx); sum += e[k]; }
        float inv = 1.0f / sum;
        #pragma unroll
        for (int k = 0; k < MM; ++k) row[k] = e[k] * inv;
    }
    __syncthreads();

    // ---- Phase D: ctx + relu + sigmoid(gate) -> gc planes (reuse a1hi/a1lo) ----
    {
        const int c = t;            // 0..255
        const int h = c >> 6;       // wave-uniform
        float cv[MM];
        #pragma unroll
        for (int k = 0; k < MM; ++k) cv[k] = tg[k][256 + c];
        #pragma unroll
        for (int m = 0; m < MM; ++m) {
            float s = 0.f;
            #pragma unroll
            for (int k = 0; k < MM; ++k) s += scr[h][m][k] * cv[k];
            float gv = tg[m][c];
            float gt = 1.0f / (1.0f + __expf(-gv));
            float gc = gt * fmaxf(s, 0.f);
            unsigned short hh = bf16_rne(gc);
            a1hi[m * PLD + c] = (short)hh;
            a1lo[m * PLD + c] = (short)bf16_rne(gc - bf16f(hh));
        }
    }
    __syncthreads();

    // ---- Phase E: summed = gc @ W_final + b_final (split-bf16 MFMA, wave w -> col tile) --
    {
        const bf16x8* WFP = (const bf16x8*)wfpk;
        f32x4 acc = {0.f, 0.f, 0.f, 0.f};
        #pragma unroll 2
        for (int ks = 0; ks < 8; ++ks) {
            bf16x8 Ah = {0,0,0,0,0,0,0,0}, Al = Ah;
            if (lr < 12) {
                const int col = ks * 32 + kg * 8;
                Ah = *(const bf16x8*)&a1hi[lr * PLD + col];
                Al = *(const bf16x8*)&a1lo[lr * PLD + col];
            }
            bf16x8 Bh = WFP[(w * 8 + ks) * 128 + lane];
            bf16x8 Bl = WFP[(w * 8 + ks) * 128 + 64 + lane];
            acc = __builtin_amdgcn_mfma_f32_16x16x32_bf16(Ah, Bh, acc, 0, 0, 0);
            acc = __builtin_amdgcn_mfma_f32_16x16x32_bf16(Ah, Bl, acc, 0, 0, 0);
            acc = __builtin_amdgcn_mfma_f32_16x16x32_bf16(Al, Bh, acc, 0, 0, 0);
        }
        const int n = w * 16 + lr;
        const float bf = b_final[n];
        if (kg < 3) {
            #pragma unroll
            for (int r = 0; r < 4; ++r)
                pre[(bn * MM + kg * 4 + r) * HAc + n] = acc[r] + bf;
        }
    }
}

// ---------------- K2: BN1 batch stats over 49152 rows ----------------
__global__ __launch_bounds__(256) void k2_stats1(const float* __restrict__ pre,
                                                 float* __restrict__ stats1)
{
    const int t  = threadIdx.x;
    const int j  = t & 63;
    const int rg = t >> 6;
    const int base = blockIdx.x * 192 + rg;
    float s = 0.f, q = 0.f;
    for (int i = 0; i < 48; ++i) {
        float v = pre[(base + i * 4) * HAc + j];
        s += v; q += v * v;
    }
    __shared__ float red[2][4][64];
    red[0][rg][j] = s;
    red[1][rg][j] = q;
    __syncthreads();
    if (t < 64) {
        float S = red[0][0][j] + red[0][1][j] + red[0][2][j] + red[0][3][j];
        float Q = red[1][0][j] + red[1][1][j] + red[1][2][j] + red[1][3][j];
        atomicAdd(&stats1[j], S);
        atomicAdd(&stats1[64 + j], Q);
    }
}

// ---------------- K3: BN1 apply + relu + sum over M; BN2 stats ----------------
__global__ __launch_bounds__(256) void k3_bn1_sum(const float* __restrict__ pre,
                                                  const float* __restrict__ stats1,
                                                  const float* __restrict__ g1,
                                                  const float* __restrict__ b1,
                                                  float* __restrict__ tout,     // [B*N,64]
                                                  float* __restrict__ stats2)
{
    const int t  = threadIdx.x;
    const int j  = t & 63;
    const int rg = t >> 6;
    const float invR = 1.0f / 49152.0f;
    const float mean = stats1[j] * invR;
    const float var  = stats1[64 + j] * invR - mean * mean;
    const float rstd = rsqrtf(var + 1e-5f);
    const float ga = g1[j], be = b1[j];

    float s2 = 0.f, q2 = 0.f;
    for (int i = 0; i < 4; ++i) {
        const int bnrow = blockIdx.x * 16 + rg + i * 4;
        float s = 0.f;
        #pragma unroll
        for (int m = 0; m < MM; ++m) {
            float x = pre[(bnrow * MM + m) * HAc + j];
            float y = (x - mean) * rstd * ga + be;
            s += fmaxf(y, 0.f);
        }
        tout[bnrow * HAc + j] = s;
        s2 += s; q2 += s * s;
    }
    __shared__ float red[2][4][64];
    red[0][rg][j] = s2;
    red[1][rg][j] = q2;
    __syncthreads();
    if (t < 64) {
        float S = red[0][0][j] + red[0][1][j] + red[0][2][j] + red[0][3][j];
        float Q = red[1][0][j] + red[1][1][j] + red[1][2][j] + red[1][3][j];
        atomicAdd(&stats2[j], S);
        atomicAdd(&stats2[64 + j], Q);
    }
}

// ---------------- K4: BN2 apply + residual + relu -> out (float4) ----------------
__global__ __launch_bounds__(256) void k4_bn2_out(const float* __restrict__ tin,
                                                  const float* __restrict__ stats2,
                                                  const float* __restrict__ g2,
                                                  const float* __restrict__ b2,
                                                  const float* __restrict__ atom_emb,
                                                  float* __restrict__ out)
{
    const int i4 = blockIdx.x * 256 + threadIdx.x;   // 65536 float4
    const int j0 = (i4 & 15) * 4;
    const float invR = 1.0f / 4096.0f;
    float4 tv = ((const float4*)tin)[i4];
    float4 ae = ((const float4*)atom_emb)[i4];
    float4 r;
    {
        float mean = stats2[j0] * invR;
        float var  = stats2[64 + j0] * invR - mean * mean;
        r.x = fmaxf(ae.x + (tv.x - mean) * rsqrtf(var + 1e-5f) * g2[j0] + b2[j0], 0.f);
    }
    {
        float mean = stats2[j0 + 1] * invR;
        float var  = stats2[64 + j0 + 1] * invR - mean * mean;
        r.y = fmaxf(ae.y + (tv.y - mean) * rsqrtf(var + 1e-5f) * g2[j0 + 1] + b2[j0 + 1], 0.f);
    }
    {
        float mean = stats2[j0 + 2] * invR;
        float var  = stats2[64 + j0 + 2] * invR - mean * mean;
        r.z = fmaxf(ae.z + (tv.z - mean) * rsqrtf(var + 1e-5f) * g2[j0 + 2] + b2[j0 + 2], 0.f);
    }
    {
        float mean = stats2[j0 + 3] * invR;
        float var  = stats2[64 + j0 + 3] * invR - mean * mean;
        r.w = fmaxf(ae.w + (tv.w - mean) * rsqrtf(var + 1e-5f) * g2[j0 + 3] + b2[j0 + 3], 0.f);
    }
    ((float4*)out)[i4] = r;
}

extern "C" void kernel_launch(void* const* d_in, const int* in_sizes, int n_in,
                              void* d_out, int out_size, void* d_ws, size_t ws_size,
                              hipStream_t stream)
{
    const float* atom_emb = (const float*)d_in[0];
    const float* nbr_emb  = (const float*)d_in[1];
    const float* atom_msk = (const float*)d_in[2];
    const float* W_full   = (const float*)d_in[3];
    const float* b_full   = (const float*)d_in[4];
    const float* W_final  = (const float*)d_in[5];
    const float* b_final  = (const float*)d_in[6];
    const float* bn1_g    = (const float*)d_in[7];
    const float* bn1_b    = (const float*)d_in[8];
    const float* bn2_g    = (const float*)d_in[9];
    const float* bn2_b    = (const float*)d_in[10];
    const int*   adj      = (const int*)d_in[11];
    float* out = (float*)d_out;

    float* ws     = (float*)d_ws;
    float* stats1 = ws;                        // 128
    float* stats2 = ws + 128;                  // 128
    float* p1b    = ws + 256;                  // 4,194,304 floats
    float* p2     = p1b + 4194304;             // 4,194,304 floats
    float* pre    = p2 + 4194304;              // 3,145,728 floats
    short* w3pk   = (short*)(pre + 3145728);   // 131,072 shorts
    short* wfpk   = w3pk + 131072;             //  32,768 shorts
    short* w12pk  = wfpk + 32768;              // 262,144 shorts
    float* tout   = p1b;                       // alias: p1b dead after k1

    hipMemsetAsync(ws, 0, 256 * sizeof(float), stream);

    k0a_pack<<<208, 256, 0, stream>>>(W_full, W_final, w12pk, w3pk, wfpk);
    k0b_p12<<<256, 256, 0, stream>>>(atom_emb, b_full, w12pk, p1b, p2);
    k1_fused<<<BB * NN, 256, 0, stream>>>(nbr_emb, atom_msk, p1b, p2, w3pk, wfpk,
                                          b_final, adj, pre);
    k2_stats1<<<256, 256, 0, stream>>>(pre, stats1);
    k3_bn1_sum<<<256, 256, 0, stream>>>(pre, stats1, bn1_g, bn1_b, tout, stats2);
    k4_bn2_out<<<256, 256, 0, stream>>>(tout, stats2, bn2_g, bn2_b, atom_emb, out);
}

// Round 9
// 211.603 us; speedup vs baseline: 1.3601x; 1.0693x over previous
//
#include <hip/hip_runtime.h>
#include <hip/hip_bf16.h>

// Problem constants (fixed by the reference)
#define BB   16
#define NN   256
#define MM   12
#define HAc  64
#define Hh   4

#define PLD  264   // plane row stride in shorts (528B, 16B-aligned)
#define TGLD 521   // tg row stride in floats

typedef __attribute__((ext_vector_type(8))) short bf16x8;   // 8 bf16 = 4 VGPRs
typedef __attribute__((ext_vector_type(4))) float f32x4;

// HW bf16 convert (RNE on gfx950); compiler can fuse pairs to v_cvt_pk_bf16_f32
__device__ __forceinline__ unsigned short f2bf(float x) {
    return __builtin_bit_cast(unsigned short, __float2bfloat16(x));
}
__device__ __forceinline__ float bf16f(unsigned short h) {
    unsigned u = ((unsigned)h) << 16;
    return __builtin_bit_cast(float, u);
}
// split 8 fp32 into hi/lo bf16 fragments (a ~= hi + lo)
__device__ __forceinline__ void split8(float4 a, float4 b, bf16x8& hi, bf16x8& lo) {
    float v[8] = {a.x, a.y, a.z, a.w, b.x, b.y, b.z, b.w};
    #pragma unroll
    for (int j = 0; j < 8; ++j) {
        unsigned short h = f2bf(v[j]);
        hi[j] = (short)h;
        lo[j] = (short)f2bf(v[j] - bf16f(h));
    }
}

// ---------------- k0a: pack weights + zero stats ----------------
// blocks 0..127:   W12 -> w12pk ; 128..191: W3 -> w3pk ; 192..207: W_final -> wfpk
// blocks 208..240: zero stats2[128] + stats1b[64*128] (ws is 0xAA-poisoned)
__global__ __launch_bounds__(256) void k0a_pack(
    const float* __restrict__ W_full,     // [192,1024]
    const float* __restrict__ W_final,    // [256,64]
    short* __restrict__ w12pk,
    short* __restrict__ w3pk,
    short* __restrict__ wfpk,
    float* __restrict__ zbase)            // stats2 + stats1b, 8320 floats
{
    const int t = threadIdx.x;
    if (blockIdx.x < 128) {
        const int gid  = blockIdx.x * 256 + t;
        const int lane = gid & 63;
        const int rest = gid >> 6;
        const int p  = rest & 1;
        const int ks = (rest >> 1) & 1;
        const int nt = rest >> 2;                  // 0..127
        const int rbase = (nt >= 64 ? 64 : 0) + ks * 32 + (lane >> 4) * 8;
        const int n  = (nt & 63) * 16 + (lane & 15);
        bf16x8 o;
        #pragma unroll
        for (int j = 0; j < 8; ++j) {
            float v = W_full[(rbase + j) * 1024 + n];
            unsigned short h = f2bf(v);
            o[j] = p ? (short)f2bf(v - bf16f(h)) : (short)h;
        }
        *((bf16x8*)(w12pk + ((nt * 4 + ks * 2 + p) * 64 + lane) * 8)) = o;
    } else if (blockIdx.x < 192) {
        const int gid  = (blockIdx.x - 128) * 256 + t;
        const int lane = gid & 63;
        const int rest = gid >> 6;
        const int p  = rest & 1;
        const int ks = (rest >> 1) & 1;
        const int nt = rest >> 2;                  // 0..63
        const int kb = ks * 32 + (lane >> 4) * 8;
        const int n  = nt * 16 + (lane & 15);
        bf16x8 o;
        #pragma unroll
        for (int j = 0; j < 8; ++j) {
            float v = W_full[(128 + kb + j) * 1024 + n];
            unsigned short h = f2bf(v);
            o[j] = p ? (short)f2bf(v - bf16f(h)) : (short)h;
        }
        *((bf16x8*)(w3pk + ((nt * 4 + ks * 2 + p) * 64 + lane) * 8)) = o;
    } else if (blockIdx.x < 208) {
        const int idx  = (blockIdx.x - 192) * 256 + t;
        const int lane = idx & 63;
        const int rest = idx >> 6;
        const int p  = rest & 1;
        const int ks = (rest >> 1) & 7;
        const int nt = rest >> 4;                  // 0..3
        const int kb = ks * 32 + (lane >> 4) * 8;
        const int n  = nt * 16 + (lane & 15);
        bf16x8 o;
        #pragma unroll
        for (int j = 0; j < 8; ++j) {
            float v = W_final[(kb + j) * 64 + n];
            unsigned short h = f2bf(v);
            o[j] = p ? (short)f2bf(v - bf16f(h)) : (short)h;
        }
        *((bf16x8*)(wfpk + ((nt * 8 + ks) * 2 + p) * 512 + lane * 8)) = o;
    } else {
        const int gid = (blockIdx.x - 208) * 256 + t;   // [0, 8448)
        if (gid < 8320) zbase[gid] = 0.f;
    }
}

// ---------------- k0b: P1b = atom_emb@W1 + b_full ; P2 = atom_emb@W2 (MFMA) ----
// grid (256, 2): 16 atom rows per x-block; y selects 16-nt half per wave.
__global__ __launch_bounds__(256) void k0b_p12(
    const float* __restrict__ atom_emb,   // [4096,64]
    const float* __restrict__ b_full,     // [1024]
    const short* __restrict__ w12pk,
    float* __restrict__ p1b,              // [4096,1024]
    float* __restrict__ p2)               // [4096,1024]
{
    const int r0   = blockIdx.x * 16;
    const int t    = threadIdx.x;
    const int w    = t >> 6;
    const int lane = t & 63;
    const int lr   = lane & 15;
    const int kg   = lane >> 4;

    bf16x8 aAh[2], aAl[2];
    #pragma unroll
    for (int ks = 0; ks < 2; ++ks) {
        const float4* ap = (const float4*)(atom_emb + (r0 + lr) * 64 + ks * 32 + kg * 8);
        split8(ap[0], ap[1], aAh[ks], aAl[ks]);
    }

    const bf16x8* W12P = (const bf16x8*)w12pk;
    #pragma unroll 4
    for (int i = 0; i < 16; ++i) {
        const int nt = w * 32 + blockIdx.y * 16 + i;
        bf16x8 Bh0 = W12P[(nt * 4 + 0) * 64 + lane];
        bf16x8 Bl0 = W12P[(nt * 4 + 1) * 64 + lane];
        bf16x8 Bh1 = W12P[(nt * 4 + 2) * 64 + lane];
        bf16x8 Bl1 = W12P[(nt * 4 + 3) * 64 + lane];
        const int n = (nt & 63) * 16 + lr;
        f32x4 acc;
        if (nt < 64) {
            float bv = b_full[n];
            acc[0] = bv; acc[1] = bv; acc[2] = bv; acc[3] = bv;
        } else {
            acc[0] = 0.f; acc[1] = 0.f; acc[2] = 0.f; acc[3] = 0.f;
        }
        acc = __builtin_amdgcn_mfma_f32_16x16x32_bf16(aAh[0], Bh0, acc, 0, 0, 0);
        acc = __builtin_amdgcn_mfma_f32_16x16x32_bf16(aAh[0], Bl0, acc, 0, 0, 0);
        acc = __builtin_amdgcn_mfma_f32_16x16x32_bf16(aAl[0], Bh0, acc, 0, 0, 0);
        acc = __builtin_amdgcn_mfma_f32_16x16x32_bf16(aAh[1], Bh1, acc, 0, 0, 0);
        acc = __builtin_amdgcn_mfma_f32_16x16x32_bf16(aAh[1], Bl1, acc, 0, 0, 0);
        acc = __builtin_amdgcn_mfma_f32_16x16x32_bf16(aAl[1], Bh1, acc, 0, 0, 0);
        float* dst = (nt < 64) ? p1b : p2;
        #pragma unroll
        for (int r = 0; r < 4; ++r)
            dst[(r0 + kg * 4 + r) * 1024 + n] = acc[r];
    }
}

// ---------------- k1: fused bond-GEMM + attention + gating + final GEMM + BN1 stats ----
__global__ __launch_bounds__(256) void k1_fused(
    const float* __restrict__ nbr_emb,    // [B,N,M,64]
    const float* __restrict__ atom_mask,  // [B,N,1]
    const float* __restrict__ p1b,
    const float* __restrict__ p2,
    const short* __restrict__ w3pk,
    const short* __restrict__ wfpk,
    const float* __restrict__ b_final,    // [64]
    const int*   __restrict__ adj,        // [B,N,M]
    float* __restrict__ pre,              // [B,N,M,64] pre-BN1
    float* __restrict__ stats1b)          // [64 bins][128] partial BN1 stats
{
    __shared__ __align__(16) float tg[12][TGLD];       // gate 0-255, core 256-511
    __shared__ __align__(16) short a1hi[12 * PLD];
    __shared__ __align__(16) short a1lo[12 * PLD];
    __shared__ __align__(16) short a2hi[12 * PLD];
    __shared__ __align__(16) short a2lo[12 * PLD];
    __shared__ float scr[Hh][MM][MM];

    const int bn   = blockIdx.x;
    const int b    = bn >> 8;
    const int t    = threadIdx.x;
    const int w    = t >> 6;
    const int lane = t & 63;
    const int lr   = lane & 15;
    const int kg   = lane >> 4;
    const float mask = atom_mask[bn];

    bf16x8 nAhi[2], nAlo[2];
    #pragma unroll
    for (int ks = 0; ks < 2; ++ks) {
        float4 v0 = make_float4(0.f, 0.f, 0.f, 0.f), v1 = v0;
        if (lr < 12) {
            const float4* np = (const float4*)(nbr_emb + bn * 768 + lr * 64 + ks * 32 + kg * 8);
            v0 = np[0]; v1 = np[1];
        }
        split8(v0, v1, nAhi[ks], nAlo[ks]);
    }

    int nr[4];
    #pragma unroll
    for (int r = 0; r < 4; ++r) {
        int m = kg * 4 + r;
        nr[r] = (m < 12) ? (b * NN + adj[bn * MM + m]) : 0;
    }

    // ---- Phase B ----
    {
        const bf16x8* W3P = (const bf16x8*)w3pk;
        #pragma unroll 4
        for (int i = 0; i < 16; ++i) {
            const int nt = w * 16 + i;
            const int n  = nt * 16 + lr;
            bf16x8 B0h = W3P[(nt * 4 + 0) * 64 + lane];
            bf16x8 B0l = W3P[(nt * 4 + 1) * 64 + lane];
            bf16x8 B1h = W3P[(nt * 4 + 2) * 64 + lane];
            bf16x8 B1l = W3P[(nt * 4 + 3) * 64 + lane];
            const float p1v = p1b[bn * 1024 + n];
            f32x4 acc;
            #pragma unroll
            for (int r = 0; r < 4; ++r) {
                float pv = (kg * 4 + r < 12) ? p2[nr[r] * 1024 + n] : 0.f;
                acc[r] = p1v + mask * pv;
            }
            acc = __builtin_amdgcn_mfma_f32_16x16x32_bf16(nAhi[0], B0h, acc, 0, 0, 0);
            acc = __builtin_amdgcn_mfma_f32_16x16x32_bf16(nAhi[0], B0l, acc, 0, 0, 0);
            acc = __builtin_amdgcn_mfma_f32_16x16x32_bf16(nAlo[0], B0h, acc, 0, 0, 0);
            acc = __builtin_amdgcn_mfma_f32_16x16x32_bf16(nAhi[1], B1h, acc, 0, 0, 0);
            acc = __builtin_amdgcn_mfma_f32_16x16x32_bf16(nAhi[1], B1l, acc, 0, 0, 0);
            acc = __builtin_amdgcn_mfma_f32_16x16x32_bf16(nAlo[1], B1h, acc, 0, 0, 0);
            if (kg < 3) {
                if (w < 2) {
                    #pragma unroll
                    for (int r = 0; r < 4; ++r) tg[kg * 4 + r][n] = acc[r];
                } else {
                    const int cl = i * 16 + lr;
                    short* phi = (w == 2) ? a1hi : a2hi;
                    short* plo = (w == 2) ? a1lo : a2lo;
                    #pragma unroll
                    for (int r = 0; r < 4; ++r) {
                        const int row = kg * 4 + r;
                        unsigned short h = f2bf(acc[r]);
                        phi[row * PLD + cl] = (short)h;
                        plo[row * PLD + cl] = (short)f2bf(acc[r] - bf16f(h));
                    }
                }
            }
        }
    }
    __syncthreads();

    // ---- Phase C: scores via MFMA, wave w = head h ----
    {
        const int h = w;
        f32x4 sc = {0.f, 0.f, 0.f, 0.f};
        #pragma unroll
        for (int ks = 0; ks < 2; ++ks) {
            bf16x8 x1h = {0,0,0,0,0,0,0,0}, x1l = x1h, x2h = x1h, x2l = x1h;
            if (lr < 12) {
                const int col = h * 64 + ks * 32 + kg * 8;
                x1h = *(const bf16x8*)&a1hi[lr * PLD + col];
                x1l = *(const bf16x8*)&a1lo[lr * PLD + col];
                x2h = *(const bf16x8*)&a2hi[lr * PLD + col];
                x2l = *(const bf16x8*)&a2lo[lr * PLD + col];
            }
            sc = __builtin_amdgcn_mfma_f32_16x16x32_bf16(x1h, x2h, sc, 0, 0, 0);
            sc = __builtin_amdgcn_mfma_f32_16x16x32_bf16(x1h, x2l, sc, 0, 0, 0);
            sc = __builtin_amdgcn_mfma_f32_16x16x32_bf16(x1l, x2h, sc, 0, 0, 0);
        }
        const float bias = (1.0f - mask) * (-10000.0f);
        if (kg < 3 && lr < 12) {
            #pragma unroll
            for (int r = 0; r < 4; ++r)
                scr[w][kg * 4 + r][lr] = 0.5f * sc[r] + bias;
        }
    }
    __syncthreads();

    // ---- softmax over k ----
    if (t < Hh * MM) {
        float* row = &scr[0][0][0] + t * MM;
        float mx = row[0];
        #pragma unroll
        for (int k = 1; k < MM; ++k) mx = fmaxf(mx, row[k]);
        float e[MM];
        float sum = 0.f;
        #pragma unroll
        for (int k = 0; k < MM; ++k) { e[k] = __expf(row[k] - mx); sum += e[k]; }
        float inv = 1.0f / sum;
        #pragma unroll
        for (int k = 0; k < MM; ++k) row[k] = e[k] * inv;
    }
    __syncthreads();

    // ---- Phase D: ctx + relu + sigmoid(gate) -> gc planes (reuse a1hi/a1lo) ----
    {
        const int c = t;
        const int h = c >> 6;
        float cv[MM];
        #pragma unroll
        for (int k = 0; k < MM; ++k) cv[k] = tg[k][256 + c];
        #pragma unroll
        for (int m = 0; m < MM; ++m) {
            float s = 0.f;
            #pragma unroll
            for (int k = 0; k < MM; ++k) s += scr[h][m][k] * cv[k];
            float gv = tg[m][c];
            float gt = 1.0f / (1.0f + __expf(-gv));
            float gc = gt * fmaxf(s, 0.f);
            unsigned short hh = f2bf(gc);
            a1hi[m * PLD + c] = (short)hh;
            a1lo[m * PLD + c] = (short)f2bf(gc - bf16f(hh));
        }
    }
    __syncthreads();

    // ---- Phase E: summed = gc @ W_final + b_final; fused BN1 stats ----
    {
        const bf16x8* WFP = (const bf16x8*)wfpk;
        f32x4 acc = {0.f, 0.f, 0.f, 0.f};
        #pragma unroll 2
        for (int ks = 0; ks < 8; ++ks) {
            bf16x8 Ah = {0,0,0,0,0,0,0,0}, Al = Ah;
            if (lr < 12) {
                const int col = ks * 32 + kg * 8;
                Ah = *(const bf16x8*)&a1hi[lr * PLD + col];
                Al = *(const bf16x8*)&a1lo[lr * PLD + col];
            }
            bf16x8 Bh = WFP[(w * 8 + ks) * 128 + lane];
            bf16x8 Bl = WFP[(w * 8 + ks) * 128 + 64 + lane];
            acc = __builtin_amdgcn_mfma_f32_16x16x32_bf16(Ah, Bh, acc, 0, 0, 0);
            acc = __builtin_amdgcn_mfma_f32_16x16x32_bf16(Ah, Bl, acc, 0, 0, 0);
            acc = __builtin_amdgcn_mfma_f32_16x16x32_bf16(Al, Bh, acc, 0, 0, 0);
        }
        const int n = w * 16 + lr;
        const float bf = b_final[n];
        float ssum = 0.f, ssq = 0.f;
        if (kg < 3) {
            #pragma unroll
            for (int r = 0; r < 4; ++r) {
                float v = acc[r] + bf;
                pre[(bn * MM + kg * 4 + r) * HAc + n] = v;
                ssum += v; ssq += v * v;
            }
        }
        // cross-kg butterfly (lane = kg*16 + lr): sum kg groups 0..3 (kg=3 contributes 0)
        ssum += __shfl_xor(ssum, 16); ssum += __shfl_xor(ssum, 32);
        ssq  += __shfl_xor(ssq, 16);  ssq  += __shfl_xor(ssq, 32);
        if (kg == 0) {
            const int bin = bn & 63;
            atomicAdd(&stats1b[bin * 128 + n], ssum);
            atomicAdd(&stats1b[bin * 128 + 64 + n], ssq);
        }
    }
}

// ---------------- K3: bin-reduce stats1 + BN1 apply + relu + sum over M; BN2 stats ----
__global__ __launch_bounds__(256) void k3_bn1_sum(const float* __restrict__ pre,
                                                  const float* __restrict__ stats1b,
                                                  const float* __restrict__ g1,
                                                  const float* __restrict__ b1,
                                                  float* __restrict__ tout,     // [B*N,64]
                                                  float* __restrict__ stats2)
{
    const int t  = threadIdx.x;
    const int j  = t & 63;
    const int rg = t >> 6;

    __shared__ float sst[128];
    if (t < 128) {
        float s = 0.f;
        for (int bin = 0; bin < 64; ++bin) s += stats1b[bin * 128 + t];
        sst[t] = s;
    }
    __syncthreads();

    const float invR = 1.0f / 49152.0f;
    const float mean = sst[j] * invR;
    const float var  = sst[64 + j] * invR - mean * mean;
    const float rstd = rsqrtf(var + 1e-5f);
    const float ga = g1[j], be = b1[j];

    float s2 = 0.f, q2 = 0.f;
    for (int i = 0; i < 4; ++i) {
        const int bnrow = blockIdx.x * 16 + rg + i * 4;
        float s = 0.f;
        #pragma unroll
        for (int m = 0; m < MM; ++m) {
            float x = pre[(bnrow * MM + m) * HAc + j];
            float y = (x - mean) * rstd * ga + be;
            s += fmaxf(y, 0.f);
        }
        tout[bnrow * HAc + j] = s;
        s2 += s; q2 += s * s;
    }
    __shared__ float red[2][4][64];
    red[0][rg][j] = s2;
    red[1][rg][j] = q2;
    __syncthreads();
    if (t < 64) {
        float S = red[0][0][j] + red[0][1][j] + red[0][2][j] + red[0][3][j];
        float Q = red[1][0][j] + red[1][1][j] + red[1][2][j] + red[1][3][j];
        atomicAdd(&stats2[j], S);
        atomicAdd(&stats2[64 + j], Q);
    }
}

// ---------------- K4: BN2 apply + residual + relu -> out (float4) ----------------
__global__ __launch_bounds__(256) void k4_bn2_out(const float* __restrict__ tin,
                                                  const float* __restrict__ stats2,
                                                  const float* __restrict__ g2,
                                                  const float* __restrict__ b2,
                                                  const float* __restrict__ atom_emb,
                                                  float* __restrict__ out)
{
    const int i4 = blockIdx.x * 256 + threadIdx.x;
    const int j0 = (i4 & 15) * 4;
    const float invR = 1.0f / 4096.0f;
    float4 tv = ((const float4*)tin)[i4];
    float4 ae = ((const float4*)atom_emb)[i4];
    float4 r;
    {
        float mean = stats2[j0] * invR;
        float var  = stats2[64 + j0] * invR - mean * mean;
        r.x = fmaxf(ae.x + (tv.x - mean) * rsqrtf(var + 1e-5f) * g2[j0] + b2[j0], 0.f);
    }
    {
        float mean = stats2[j0 + 1] * invR;
        float var  = stats2[64 + j0 + 1] * invR - mean * mean;
        r.y = fmaxf(ae.y + (tv.y - mean) * rsqrtf(var + 1e-5f) * g2[j0 + 1] + b2[j0 + 1], 0.f);
    }
    {
        float mean = stats2[j0 + 2] * invR;
        float var  = stats2[64 + j0 + 2] * invR - mean * mean;
        r.z = fmaxf(ae.z + (tv.z - mean) * rsqrtf(var + 1e-5f) * g2[j0 + 2] + b2[j0 + 2], 0.f);
    }
    {
        float mean = stats2[j0 + 3] * invR;
        float var  = stats2[64 + j0 + 3] * invR - mean * mean;
        r.w = fmaxf(ae.w + (tv.w - mean) * rsqrtf(var + 1e-5f) * g2[j0 + 3] + b2[j0 + 3], 0.f);
    }
    ((float4*)out)[i4] = r;
}

extern "C" void kernel_launch(void* const* d_in, const int* in_sizes, int n_in,
                              void* d_out, int out_size, void* d_ws, size_t ws_size,
                              hipStream_t stream)
{
    const float* atom_emb = (const float*)d_in[0];
    const float* nbr_emb  = (const float*)d_in[1];
    const float* atom_msk = (const float*)d_in[2];
    const float* W_full   = (const float*)d_in[3];
    const float* b_full   = (const float*)d_in[4];
    const float* W_final  = (const float*)d_in[5];
    const float* b_final  = (const float*)d_in[6];
    const float* bn1_g    = (const float*)d_in[7];
    const float* bn1_b    = (const float*)d_in[8];
    const float* bn2_g    = (const float*)d_in[9];
    const float* bn2_b    = (const float*)d_in[10];
    const int*   adj      = (const int*)d_in[11];
    float* out = (float*)d_out;

    float* ws      = (float*)d_ws;
    float* stats2  = ws;                       // 128
    float* stats1b = ws + 128;                 // 64*128 = 8192
    float* p1b     = ws + 8320;                // 4,194,304
    float* p2      = p1b + 4194304;            // 4,194,304
    float* pre     = p2 + 4194304;             // 3,145,728
    short* w3pk    = (short*)(pre + 3145728);  // 131,072 shorts
    short* wfpk    = w3pk + 131072;            //  32,768 shorts
    short* w12pk   = wfpk + 32768;             // 262,144 shorts
    float* tout    = p1b;                      // alias: p1b dead after k1

    k0a_pack<<<241, 256, 0, stream>>>(W_full, W_final, w12pk, w3pk, wfpk, ws);
    k0b_p12<<<dim3(256, 2), 256, 0, stream>>>(atom_emb, b_full, w12pk, p1b, p2);
    k1_fused<<<BB * NN, 256, 0, stream>>>(nbr_emb, atom_msk, p1b, p2, w3pk, wfpk,
                                          b_final, adj, pre, stats1b);
    k3_bn1_sum<<<256, 256, 0, stream>>>(pre, stats1b, bn1_g, bn1_b, tout, stats2);
    k4_bn2_out<<<256, 256, 0, stream>>>(tout, stats2, bn2_g, bn2_b, atom_emb, out);
}

// Round 12
// 198.434 us; speedup vs baseline: 1.4503x; 1.0664x over previous
//
#include <hip/hip_runtime.h>
#include <hip/hip_bf16.h>

// Problem constants (fixed by the reference)
#define BB   16
#define NN   256
#define MM   12
#define HAc  64
#define Hh   4

#define PLD  264   // plane row stride in shorts (528B, 16B-aligned)
#define TGLD 521   // tg row stride in floats

typedef __attribute__((ext_vector_type(8))) short bf16x8;   // 8 bf16 = 4 VGPRs
typedef __attribute__((ext_vector_type(4))) float f32x4;

// HW bf16 convert (RNE); compiler fuses pairs to v_cvt_pk_bf16_f32
__device__ __forceinline__ unsigned short f2bf(float x) {
    return __builtin_bit_cast(unsigned short, __float2bfloat16(x));
}
__device__ __forceinline__ float bf16f(unsigned short h) {
    unsigned u = ((unsigned)h) << 16;
    return __builtin_bit_cast(float, u);
}
// split 8 fp32 into hi/lo bf16 fragments (a ~= hi + lo)
__device__ __forceinline__ void split8(float4 a, float4 b, bf16x8& hi, bf16x8& lo) {
    float v[8] = {a.x, a.y, a.z, a.w, b.x, b.y, b.z, b.w};
    #pragma unroll
    for (int j = 0; j < 8; ++j) {
        unsigned short h = f2bf(v[j]);
        hi[j] = (short)h;
        lo[j] = (short)f2bf(v[j] - bf16f(h));
    }
}

// ---------------- k0: merged prep (all blocks independent) ----------------
// blocks 0..511:   P1b = atom_emb@W1 + b_full ; P2 = atom_emb@W2 (MFMA, self-packed B)
// blocks 512..575: pack W3 -> w3pk
// blocks 576..591: pack W_final -> wfpk
// blocks 592..624: zero stats2[128] + stats1b[64*128]
__global__ __launch_bounds__(256) void k0_prep(
    const float* __restrict__ atom_emb,   // [4096,64]
    const float* __restrict__ W_full,     // [192,1024]
    const float* __restrict__ b_full,     // [1024]
    const float* __restrict__ W_final,    // [256,64]
    float* __restrict__ p1b,              // [4096,1024]
    float* __restrict__ p2,               // [4096,1024]
    short* __restrict__ w3pk,
    short* __restrict__ wfpk,
    float* __restrict__ zbase)            // stats2 + stats1b, 8320 floats
{
    const int t = threadIdx.x;
    if (blockIdx.x < 512) {
        const int q    = blockIdx.x;
        const int r0   = (q >> 1) * 16;     // 16 atom rows
        const int half = q & 1;             // nt half per wave
        const int w    = t >> 6;
        const int lane = t & 63;
        const int lr   = lane & 15;
        const int kg   = lane >> 4;

        bf16x8 aAh[2], aAl[2];
        #pragma unroll
        for (int ks = 0; ks < 2; ++ks) {
            const float4* ap = (const float4*)(atom_emb + (r0 + lr) * 64 + ks * 32 + kg * 8);
            split8(ap[0], ap[1], aAh[ks], aAl[ks]);
        }

        #pragma unroll 4
        for (int i = 0; i < 16; ++i) {
            const int nt   = w * 32 + half * 16 + i;   // 0..127 (W1 if <64 else W2)
            const int roff = (nt >= 64) ? 64 : 0;
            const int ncol = (nt & 63) * 16 + lr;
            bf16x8 Bh0, Bl0, Bh1, Bl1;
            #pragma unroll
            for (int j = 0; j < 8; ++j) {
                float v0 = W_full[(roff + kg * 8 + j) * 1024 + ncol];
                float v1 = W_full[(roff + 32 + kg * 8 + j) * 1024 + ncol];
                unsigned short h0 = f2bf(v0);
                Bh0[j] = (short)h0; Bl0[j] = (short)f2bf(v0 - bf16f(h0));
                unsigned short h1 = f2bf(v1);
                Bh1[j] = (short)h1; Bl1[j] = (short)f2bf(v1 - bf16f(h1));
            }
            f32x4 acc;
            if (nt < 64) {
                float bv = b_full[ncol];
                acc[0] = bv; acc[1] = bv; acc[2] = bv; acc[3] = bv;
            } else {
                acc[0] = 0.f; acc[1] = 0.f; acc[2] = 0.f; acc[3] = 0.f;
            }
            acc = __builtin_amdgcn_mfma_f32_16x16x32_bf16(aAh[0], Bh0, acc, 0, 0, 0);
            acc = __builtin_amdgcn_mfma_f32_16x16x32_bf16(aAh[0], Bl0, acc, 0, 0, 0);
            acc = __builtin_amdgcn_mfma_f32_16x16x32_bf16(aAl[0], Bh0, acc, 0, 0, 0);
            acc = __builtin_amdgcn_mfma_f32_16x16x32_bf16(aAh[1], Bh1, acc, 0, 0, 0);
            acc = __builtin_amdgcn_mfma_f32_16x16x32_bf16(aAh[1], Bl1, acc, 0, 0, 0);
            acc = __builtin_amdgcn_mfma_f32_16x16x32_bf16(aAl[1], Bh1, acc, 0, 0, 0);
            float* dst = (nt < 64) ? p1b : p2;
            #pragma unroll
            for (int r = 0; r < 4; ++r)
                dst[(r0 + kg * 4 + r) * 1024 + ncol] = acc[r];
        }
    } else if (blockIdx.x < 576) {
        const int gid  = (blockIdx.x - 512) * 256 + t;   // [0,16384)
        const int lane = gid & 63;
        const int rest = gid >> 6;
        const int p  = rest & 1;
        const int ks = (rest >> 1) & 1;
        const int nt = rest >> 2;                  // 0..63
        const int kb = ks * 32 + (lane >> 4) * 8;
        const int n  = nt * 16 + (lane & 15);
        bf16x8 o;
        #pragma unroll
        for (int j = 0; j < 8; ++j) {
            float v = W_full[(128 + kb + j) * 1024 + n];
            unsigned short h = f2bf(v);
            o[j] = p ? (short)f2bf(v - bf16f(h)) : (short)h;
        }
        *((bf16x8*)(w3pk + ((nt * 4 + ks * 2 + p) * 64 + lane) * 8)) = o;
    } else if (blockIdx.x < 592) {
        const int idx  = (blockIdx.x - 576) * 256 + t;   // [0,4096)
        const int lane = idx & 63;
        const int rest = idx >> 6;
        const int p  = rest & 1;
        const int ks = (rest >> 1) & 7;
        const int nt = rest >> 4;                  // 0..3
        const int kb = ks * 32 + (lane >> 4) * 8;
        const int n  = nt * 16 + (lane & 15);
        bf16x8 o;
        #pragma unroll
        for (int j = 0; j < 8; ++j) {
            float v = W_final[(kb + j) * 64 + n];
            unsigned short h = f2bf(v);
            o[j] = p ? (short)f2bf(v - bf16f(h)) : (short)h;
        }
        *((bf16x8*)(wfpk + ((nt * 8 + ks) * 2 + p) * 512 + lane * 8)) = o;
    } else {
        const int gid = (blockIdx.x - 592) * 256 + t;   // [0, 8448)
        if (gid < 8320) zbase[gid] = 0.f;
    }
}

// ---------------- k1: fused bond-GEMM + attention + gating + final GEMM + BN1 stats ----
__global__ __launch_bounds__(256) void k1_fused(
    const float* __restrict__ nbr_emb,    // [B,N,M,64]
    const float* __restrict__ atom_mask,  // [B,N,1]
    const float* __restrict__ p1b,
    const float* __restrict__ p2,
    const short* __restrict__ w3pk,
    const short* __restrict__ wfpk,
    const float* __restrict__ b_final,    // [64]
    const int*   __restrict__ adj,        // [B,N,M]
    float* __restrict__ pre,              // [B,N,M,64] pre-BN1
    float* __restrict__ stats1b)          // [64 bins][128] partial BN1 stats
{
    __shared__ __align__(16) float tg[12][TGLD];       // gate 0-255, core 256-511
    __shared__ __align__(16) short a1hi[12 * PLD];
    __shared__ __align__(16) short a1lo[12 * PLD];
    __shared__ __align__(16) short a2hi[12 * PLD];
    __shared__ __align__(16) short a2lo[12 * PLD];
    __shared__ float scr[Hh][MM][MM];

    const int bn   = blockIdx.x;
    const int b    = bn >> 8;
    const int t    = threadIdx.x;
    const int w    = t >> 6;
    const int lane = t & 63;
    const int lr   = lane & 15;
    const int kg   = lane >> 4;
    const float mask = atom_mask[bn];

    bf16x8 nAhi[2], nAlo[2];
    #pragma unroll
    for (int ks = 0; ks < 2; ++ks) {
        float4 v0 = make_float4(0.f, 0.f, 0.f, 0.f), v1 = v0;
        if (lr < 12) {
            const float4* np = (const float4*)(nbr_emb + bn * 768 + lr * 64 + ks * 32 + kg * 8);
            v0 = np[0]; v1 = np[1];
        }
        split8(v0, v1, nAhi[ks], nAlo[ks]);
    }

    int nr[4];
    #pragma unroll
    for (int r = 0; r < 4; ++r) {
        int m = kg * 4 + r;
        nr[r] = (m < 12) ? (b * NN + adj[bn * MM + m]) : 0;
    }

    // ---- Phase B: software-pipelined. acc starts 0; P-part added AFTER MFMAs
    // (commutative) so loads are consumed at iteration end, not start. ----
    {
        const bf16x8* W3P = (const bf16x8*)w3pk;
        const float* p1row = p1b + bn * 1024;

        bf16x8 cB0h, cB0l, cB1h, cB1l; float cp1; f32x4 cp2;
        bf16x8 xB0h, xB0l, xB1h, xB1l; float xp1; f32x4 xp2;

#define PB_LOAD(IDX, B0h_, B0l_, B1h_, B1l_, P1_, P2_) do {                        \
            const int nt_ = w * 16 + (IDX);                                         \
            const int n_  = nt_ * 16 + lr;                                          \
            B0h_ = W3P[(nt_ * 4 + 0) * 64 + lane];                                  \
            B0l_ = W3P[(nt_ * 4 + 1) * 64 + lane];                                  \
            B1h_ = W3P[(nt_ * 4 + 2) * 64 + lane];                                  \
            B1l_ = W3P[(nt_ * 4 + 3) * 64 + lane];                                  \
            P1_  = p1row[n_];                                                       \
            _Pragma("unroll")                                                       \
            for (int r_ = 0; r_ < 4; ++r_)                                          \
                P2_[r_] = (kg * 4 + r_ < 12) ? p2[nr[r_] * 1024 + n_] : 0.f;        \
        } while (0)

#define PB_COMP(IDX, B0h_, B0l_, B1h_, B1l_, P1_, P2_) do {                        \
            f32x4 acc = {0.f, 0.f, 0.f, 0.f};                                       \
            acc = __builtin_amdgcn_mfma_f32_16x16x32_bf16(nAhi[0], B0h_, acc, 0, 0, 0); \
            acc = __builtin_amdgcn_mfma_f32_16x16x32_bf16(nAhi[0], B0l_, acc, 0, 0, 0); \
            acc = __builtin_amdgcn_mfma_f32_16x16x32_bf16(nAlo[0], B0h_, acc, 0, 0, 0); \
            acc = __builtin_amdgcn_mfma_f32_16x16x32_bf16(nAhi[1], B1h_, acc, 0, 0, 0); \
            acc = __builtin_amdgcn_mfma_f32_16x16x32_bf16(nAhi[1], B1l_, acc, 0, 0, 0); \
            acc = __builtin_amdgcn_mfma_f32_16x16x32_bf16(nAlo[1], B1h_, acc, 0, 0, 0); \
            const int n_ = (w * 16 + (IDX)) * 16 + lr;                              \
            if (kg < 3) {                                                           \
                if (w < 2) {                                                        \
                    _Pragma("unroll")                                               \
                    for (int r_ = 0; r_ < 4; ++r_)                                  \
                        tg[kg * 4 + r_][n_] = acc[r_] + P1_ + mask * P2_[r_];       \
                } else {                                                            \
                    const int cl_ = (IDX) * 16 + lr;                                \
                    short* phi_ = (w == 2) ? a1hi : a2hi;                           \
                    short* plo_ = (w == 2) ? a1lo : a2lo;                           \
                    _Pragma("unroll")                                               \
                    for (int r_ = 0; r_ < 4; ++r_) {                                \
                        float v_ = acc[r_] + P1_ + mask * P2_[r_];                  \
                        unsigned short h_ = f2bf(v_);                               \
                        phi_[(kg * 4 + r_) * PLD + cl_] = (short)h_;                \
                        plo_[(kg * 4 + r_) * PLD + cl_] = (short)f2bf(v_ - bf16f(h_)); \
                    }                                                               \
                }                                                                   \
            }                                                                       \
        } while (0)

        PB_LOAD(0, cB0h, cB0l, cB1h, cB1l, cp1, cp2);
        for (int ii = 0; ii < 8; ++ii) {
            const int i0 = 2 * ii, i1 = 2 * ii + 1;
            PB_LOAD(i1, xB0h, xB0l, xB1h, xB1l, xp1, xp2);
            PB_COMP(i0, cB0h, cB0l, cB1h, cB1l, cp1, cp2);
            const int i2 = (i1 < 15) ? i1 + 1 : 15;
            PB_LOAD(i2, cB0h, cB0l, cB1h, cB1l, cp1, cp2);
            PB_COMP(i1, xB0h, xB0l, xB1h, xB1l, xp1, xp2);
        }
#undef PB_LOAD
#undef PB_COMP
    }
    __syncthreads();

    // ---- Phase C: scores via MFMA, wave w = head h ----
    {
        const int h = w;
        f32x4 sc = {0.f, 0.f, 0.f, 0.f};
        #pragma unroll
        for (int ks = 0; ks < 2; ++ks) {
            bf16x8 x1h = {0,0,0,0,0,0,0,0}, x1l = x1h, x2h = x1h, x2l = x1h;
            if (lr < 12) {
                const int col = h * 64 + ks * 32 + kg * 8;
                x1h = *(const bf16x8*)&a1hi[lr * PLD + col];
                x1l = *(const bf16x8*)&a1lo[lr * PLD + col];
                x2h = *(const bf16x8*)&a2hi[lr * PLD + col];
                x2l = *(const bf16x8*)&a2lo[lr * PLD + col];
            }
            sc = __builtin_amdgcn_mfma_f32_16x16x32_bf16(x1h, x2h, sc, 0, 0, 0);
            sc = __builtin_amdgcn_mfma_f32_16x16x32_bf16(x1h, x2l, sc, 0, 0, 0);
            sc = __builtin_amdgcn_mfma_f32_16x16x32_bf16(x1l, x2h, sc, 0, 0, 0);
        }
        const float bias = (1.0f - mask) * (-10000.0f);
        if (kg < 3 && lr < 12) {
            #pragma unroll
            for (int r = 0; r < 4; ++r)
                scr[w][kg * 4 + r][lr] = 0.5f * sc[r] + bias;
        }
    }
    __syncthreads();

    // ---- softmax over k ----
    if (t < Hh * MM) {
        float* row = &scr[0][0][0] + t * MM;
        float mx = row[0];
        #pragma unroll
        for (int k = 1; k < MM; ++k) mx = fmaxf(mx, row[k]);
        float e[MM];
        float sum = 0.f;
        #pragma unroll
        for (int k = 0; k < MM; ++k) { e[k] = __expf(row[k] - mx); sum += e[k]; }
        float inv = 1.0f / sum;
        #pragma unroll
        for (int k = 0; k < MM; ++k) row[k] = e[k] * inv;
    }
    __syncthreads();

    // ---- Phase D: ctx + relu + sigmoid(gate) -> gc planes (reuse a1hi/a1lo) ----
    {
        const int c = t;
        const int h = c >> 6;
        float cv[MM];
        #pragma unroll
        for (int k = 0; k < MM; ++k) cv[k] = tg[k][256 + c];
        #pragma unroll
        for (int m = 0; m < MM; ++m) {
            float s = 0.f;
            #pragma unroll
            for (int k = 0; k < MM; ++k) s += scr[h][m][k] * cv[k];
            float gv = tg[m][c];
            float gt = 1.0f / (1.0f + __expf(-gv));
            float gc = gt * fmaxf(s, 0.f);
            unsigned short hh = f2bf(gc);
            a1hi[m * PLD + c] = (short)hh;
            a1lo[m * PLD + c] = (short)f2bf(gc - bf16f(hh));
        }
    }
    __syncthreads();

    // ---- Phase E: summed = gc @ W_final + b_final; fused BN1 stats ----
    {
        const bf16x8* WFP = (const bf16x8*)wfpk;
        f32x4 acc = {0.f, 0.f, 0.f, 0.f};
        #pragma unroll 2
        for (int ks = 0; ks < 8; ++ks) {
            bf16x8 Ah = {0,0,0,0,0,0,0,0}, Al = Ah;
            if (lr < 12) {
                const int col = ks * 32 + kg * 8;
                Ah = *(const bf16x8*)&a1hi[lr * PLD + col];
                Al = *(const bf16x8*)&a1lo[lr * PLD + col];
            }
            bf16x8 Bh = WFP[(w * 8 + ks) * 128 + lane];
            bf16x8 Bl = WFP[(w * 8 + ks) * 128 + 64 + lane];
            acc = __builtin_amdgcn_mfma_f32_16x16x32_bf16(Ah, Bh, acc, 0, 0, 0);
            acc = __builtin_amdgcn_mfma_f32_16x16x32_bf16(Ah, Bl, acc, 0, 0, 0);
            acc = __builtin_amdgcn_mfma_f32_16x16x32_bf16(Al, Bh, acc, 0, 0, 0);
        }
        const int n = w * 16 + lr;
        const float bf = b_final[n];
        float ssum = 0.f, ssq = 0.f;
        if (kg < 3) {
            #pragma unroll
            for (int r = 0; r < 4; ++r) {
                float v = acc[r] + bf;
                pre[(bn * MM + kg * 4 + r) * HAc + n] = v;
                ssum += v; ssq += v * v;
            }
        }
        ssum += __shfl_xor(ssum, 16); ssum += __shfl_xor(ssum, 32);
        ssq  += __shfl_xor(ssq, 16);  ssq  += __shfl_xor(ssq, 32);
        if (kg == 0) {
            const int bin = bn & 63;
            atomicAdd(&stats1b[bin * 128 + n], ssum);
            atomicAdd(&stats1b[bin * 128 + 64 + n], ssq);
        }
    }
}

// ---------------- K3: bin-reduce stats1 + BN1 apply + relu + sum over M; BN2 stats ----
__global__ __launch_bounds__(256) void k3_bn1_sum(const float* __restrict__ pre,
                                                  const float* __restrict__ stats1b,
                                                  const float* __restrict__ g1,
                                                  const float* __restrict__ b1,
                                                  float* __restrict__ tout,     // [B*N,64]
                                                  float* __restrict__ stats2)
{
    const int t  = threadIdx.x;
    const int j  = t & 63;
    const int rg = t >> 6;

    __shared__ float sst[128];
    if (t < 128) {
        float s = 0.f;
        for (int bin = 0; bin < 64; ++bin) s += stats1b[bin * 128 + t];
        sst[t] = s;
    }
    __syncthreads();

    const float invR = 1.0f / 49152.0f;
    const float mean = sst[j] * invR;
    const float var  = sst[64 + j] * invR - mean * mean;
    const float rstd = rsqrtf(var + 1e-5f);
    const float ga = g1[j], be = b1[j];

    float s2 = 0.f, q2 = 0.f;
    for (int i = 0; i < 4; ++i) {
        const int bnrow = blockIdx.x * 16 + rg + i * 4;
        float s = 0.f;
        #pragma unroll
        for (int m = 0; m < MM; ++m) {
            float x = pre[(bnrow * MM + m) * HAc + j];
            float y = (x - mean) * rstd * ga + be;
            s += fmaxf(y, 0.f);
        }
        tout[bnrow * HAc + j] = s;
        s2 += s; q2 += s * s;
    }
    __shared__ float red[2][4][64];
    red[0][rg][j] = s2;
    red[1][rg][j] = q2;
    __syncthreads();
    if (t < 64) {
        float S = red[0][0][j] + red[0][1][j] + red[0][2][j] + red[0][3][j];
        float Q = red[1][0][j] + red[1][1][j] + red[1][2][j] + red[1][3][j];
        atomicAdd(&stats2[j], S);
        atomicAdd(&stats2[64 + j], Q);
    }
}

// ---------------- K4: BN2 apply + residual + relu -> out (float4) ----------------
__global__ __launch_bounds__(256) void k4_bn2_out(const float* __restrict__ tin,
                                                  const float* __restrict__ stats2,
                                                  const float* __restrict__ g2,
                                                  const float* __restrict__ b2,
                                                  const float* __restrict__ atom_emb,
                                                  float* __restrict__ out)
{
    const int i4 = blockIdx.x * 256 + threadIdx.x;
    const int j0 = (i4 & 15) * 4;
    const float invR = 1.0f / 4096.0f;
    float4 tv = ((const float4*)tin)[i4];
    float4 ae = ((const float4*)atom_emb)[i4];
    float4 r;
    {
        float mean = stats2[j0] * invR;
        float var  = stats2[64 + j0] * invR - mean * mean;
        r.x = fmaxf(ae.x + (tv.x - mean) * rsqrtf(var + 1e-5f) * g2[j0] + b2[j0], 0.f);
    }
    {
        float mean = stats2[j0 + 1] * invR;
        float var  = stats2[64 + j0 + 1] * invR - mean * mean;
        r.y = fmaxf(ae.y + (tv.y - mean) * rsqrtf(var + 1e-5f) * g2[j0 + 1] + b2[j0 + 1], 0.f);
    }
    {
        float mean = stats2[j0 + 2] * invR;
        float var  = stats2[64 + j0 + 2] * invR - mean * mean;
        r.z = fmaxf(ae.z + (tv.z - mean) * rsqrtf(var + 1e-5f) * g2[j0 + 2] + b2[j0 + 2], 0.f);
    }
    {
        float mean = stats2[j0 + 3] * invR;
        float var  = stats2[64 + j0 + 3] * invR - mean * mean;
        r.w = fmaxf(ae.w + (tv.w - mean) * rsqrtf(var + 1e-5f) * g2[j0 + 3] + b2[j0 + 3], 0.f);
    }
    ((float4*)out)[i4] = r;
}

extern "C" void kernel_launch(void* const* d_in, const int* in_sizes, int n_in,
                              void* d_out, int out_size, void* d_ws, size_t ws_size,
                              hipStream_t stream)
{
    const float* atom_emb = (const float*)d_in[0];
    const float* nbr_emb  = (const float*)d_in[1];
    const float* atom_msk = (const float*)d_in[2];
    const float* W_full   = (const float*)d_in[3];
    const float* b_full   = (const float*)d_in[4];
    const float* W_final  = (const float*)d_in[5];
    const float* b_final  = (const float*)d_in[6];
    const float* bn1_g    = (const float*)d_in[7];
    const float* bn1_b    = (const float*)d_in[8];
    const float* bn2_g    = (const float*)d_in[9];
    const float* bn2_b    = (const float*)d_in[10];
    const int*   adj      = (const int*)d_in[11];
    float* out = (float*)d_out;

    float* ws      = (float*)d_ws;
    float* stats2  = ws;                       // 128
    float* stats1b = ws + 128;                 // 8192
    float* p1b     = ws + 8320;                // 4,194,304
    float* p2      = p1b + 4194304;            // 4,194,304
    float* pre     = p2 + 4194304;             // 3,145,728
    short* w3pk    = (short*)(pre + 3145728);  // 131,072 shorts
    short* wfpk    = w3pk + 131072;            //  32,768 shorts
    float* tout    = p1b;                      // alias: p1b dead after k1

    k0_prep<<<625, 256, 0, stream>>>(atom_emb, W_full, b_full, W_final,
                                     p1b, p2, w3pk, wfpk, ws);
    k1_fused<<<BB * NN, 256, 0, stream>>>(nbr_emb, atom_msk, p1b, p2, w3pk, wfpk,
                                          b_final, adj, pre, stats1b);
    k3_bn1_sum<<<256, 256, 0, stream>>>(pre, stats1b, bn1_g, bn1_b, tout, stats2);
    k4_bn2_out<<<256, 256, 0, stream>>>(tout, stats2, bn2_g, bn2_b, atom_emb, out);
}